// Round 4
// baseline (962.603 us; speedup 1.0000x reference)
//
#include <hip/hip_runtime.h>
#include <stdint.h>

// RWKV-4 block: B=8, T=2048, C=1024, DIM_FFN=4096, fp32 in/out, bf16 MFMA internally.
#define B_ 8
#define T_ 2048
#define C_ 1024
#define F_ 4096
#define M_ (B_*T_)   // 16384 rows
#define NC 16        // WKV chunks per sequence
#define LCH (T_/NC)  // 128 steps per chunk

typedef __attribute__((ext_vector_type(8))) short bf16x8;   // MFMA A/B frag (4 VGPRs)
typedef __attribute__((ext_vector_type(4))) float f32x4;    // MFMA C/D frag

static __device__ __forceinline__ unsigned short f2bf(float f) {
    union { float f; unsigned u; } v; v.f = f;
    unsigned r = v.u + 0x7fffu + ((v.u >> 16) & 1u);  // RNE
    return (unsigned short)(r >> 16);
}
static __device__ __forceinline__ float bf2f(unsigned short h) {
    union { unsigned u; float f; } v; v.u = ((unsigned)h) << 16;
    return v.f;
}

// async global->LDS, 16B/lane, wave-uniform LDS base + lane*16 (m97 pattern)
#define GLDS16(gp, lp) __builtin_amdgcn_global_load_lds( \
    (const __attribute__((address_space(1))) unsigned int*)(gp), \
    (__attribute__((address_space(3))) unsigned int*)(lp), 16, 0, 0)

#define SB0() __builtin_amdgcn_sched_barrier(0)
#define MFMA_BF16(a, b, c) __builtin_amdgcn_mfma_f32_16x16x32_bf16((a), (b), (c), 0, 0, 0)

// ---------------------------------------------------------------------------
// Weight conversion fp32 -> bf16 into one packed ws region (13M elems, 26MB).
// dst element layout: [Wk 1M][Wv 1M][Wr 1M][Wo 1M][Wrec 1M][Wkey 4M][Wval 4M]
// ---------------------------------------------------------------------------
struct WSrc { const float* p[7]; };

__global__ __launch_bounds__(256) void k_convert(WSrc w, unsigned short* __restrict__ dst) {
    size_t e = ((size_t)blockIdx.x * 256 + threadIdx.x) * 4;
    int seg = (int)(e >> 20);
    const float* s; size_t off;
    if (seg < 5)      { s = w.p[seg]; off = e - ((size_t)seg << 20); }
    else if (seg < 9) { s = w.p[5];   off = e - (5ull << 20); }
    else              { s = w.p[6];   off = e - (9ull << 20); }
    float4 v = *(const float4*)(s + off);
    ushort4 o;
    o.x = f2bf(v.x); o.y = f2bf(v.y); o.z = f2bf(v.z); o.w = f2bf(v.w);
    *(ushort4*)(dst + e) = o;
}

// ---------------------------------------------------------------------------
// Fused LayerNorm + time_shift + token-mix. One block per row m = b*T+t.
// ---------------------------------------------------------------------------
template<int THREE>
__global__ __launch_bounds__(256) void k_ln_mix(
    const float* __restrict__ xin, const float* __restrict__ lw, const float* __restrict__ lb,
    const float* __restrict__ tk, const float* __restrict__ tv, const float* __restrict__ tr,
    unsigned short* __restrict__ ok, unsigned short* __restrict__ ov, unsigned short* __restrict__ orr)
{
    __shared__ float sred[4][4];
    const int m = blockIdx.x;
    const int t = m & (T_ - 1);
    const int tid = threadIdx.x;
    const int col0 = tid * 4;

    const float4 xc = *(const float4*)(xin + (size_t)m * C_ + col0);
    float4 xp = make_float4(0.f, 0.f, 0.f, 0.f);
    if (t > 0) xp = *(const float4*)(xin + (size_t)(m - 1) * C_ + col0);

    float s1 = xc.x + xc.y + xc.z + xc.w;
    float s2 = xc.x*xc.x + xc.y*xc.y + xc.z*xc.z + xc.w*xc.w;
    float s3 = xp.x + xp.y + xp.z + xp.w;
    float s4 = xp.x*xp.x + xp.y*xp.y + xp.z*xp.z + xp.w*xp.w;
    #pragma unroll
    for (int off = 32; off > 0; off >>= 1) {
        s1 += __shfl_down(s1, off);
        s2 += __shfl_down(s2, off);
        s3 += __shfl_down(s3, off);
        s4 += __shfl_down(s4, off);
    }
    const int wave = tid >> 6, lane = tid & 63;
    if (lane == 0) { sred[0][wave]=s1; sred[1][wave]=s2; sred[2][wave]=s3; sred[3][wave]=s4; }
    __syncthreads();
    const float S1 = sred[0][0]+sred[0][1]+sred[0][2]+sred[0][3];
    const float S2 = sred[1][0]+sred[1][1]+sred[1][2]+sred[1][3];
    const float S3 = sred[2][0]+sred[2][1]+sred[2][2]+sred[2][3];
    const float S4 = sred[3][0]+sred[3][1]+sred[3][2]+sred[3][3];

    const float inv = 1.0f / (float)C_;
    const float muc = S1 * inv;
    const float rc  = rsqrtf(S2 * inv - muc * muc + 1e-5f);
    const float mup = S3 * inv;
    const float rp  = rsqrtf(S4 * inv - mup * mup + 1e-5f);

    const float xcv[4] = {xc.x, xc.y, xc.z, xc.w};
    const float xpv[4] = {xp.x, xp.y, xp.z, xp.w};
    unsigned short rk[4], rv[4], rr[4];
    #pragma unroll
    for (int i = 0; i < 4; ++i) {
        const int col = col0 + i;
        const float w_ = lw[col], b_ = lb[col];
        const float h  = (xcv[i] - muc) * rc * w_ + b_;
        const float hh = (t > 0) ? (xpv[i] - mup) * rp * w_ + b_ : 0.f;
        const float ak = tk[col];
        rk[i] = f2bf(h * ak + hh * (1.f - ak));
        if (THREE) { const float av = tv[col]; rv[i] = f2bf(h * av + hh * (1.f - av)); }
        const float ar = tr[col];
        rr[i] = f2bf(h * ar + hh * (1.f - ar));
    }
    const size_t o = (size_t)m * C_ + col0;
    ushort4 u;
    u.x = rk[0]; u.y = rk[1]; u.z = rk[2]; u.w = rk[3];
    *(ushort4*)(ok + o) = u;
    if (THREE) {
        u.x = rv[0]; u.y = rv[1]; u.z = rv[2]; u.w = rv[3];
        *(ushort4*)(ov + o) = u;
    }
    u.x = rr[0]; u.y = rr[1]; u.z = rr[2]; u.w = rr[3];
    *(ushort4*)(orr + o) = u;
}

// ---------------------------------------------------------------------------
// WKV pass A: per (b,c,chunk) local state recurrence from zero init.
// ---------------------------------------------------------------------------
__global__ __launch_bounds__(256) void k_wkv_local(
    const unsigned short* __restrict__ kb, const unsigned short* __restrict__ vb,
    const float* __restrict__ tdec, float4* __restrict__ st)
{
    const int g = blockIdx.x * 256 + threadIdx.x;   // 0..131071
    const int c = g & (C_ - 1);
    const int j = (g >> 10) & (NC - 1);
    const int b = g >> 14;
    const float w = -__expf(tdec[c]);
    float aa = 0.f, bb = 0.f, pp = -1e38f;
    const size_t base = ((size_t)(b * T_ + j * LCH)) * C_ + c;
    #pragma unroll 4
    for (int t = 0; t < LCH; ++t) {
        const float kt = bf2f(kb[base + (size_t)t * C_]);
        const float vt = bf2f(vb[base + (size_t)t * C_]);
        const float ww2 = pp + w;
        const float qq2 = fmaxf(ww2, kt);
        const float e1b = __expf(ww2 - qq2);
        const float e2b = __expf(kt - qq2);
        aa = e1b * aa + e2b * vt;
        bb = e1b * bb + e2b;
        pp = qq2;
    }
    st[((size_t)b * NC + j) * C_ + c] = make_float4(aa, bb, pp, 0.f);
}

// ---------------------------------------------------------------------------
// WKV pass C: combine preceding chunk states, replay chunk computing p=sr*y.
// ---------------------------------------------------------------------------
__global__ __launch_bounds__(256) void k_wkv_scan(
    const unsigned short* __restrict__ kb, const unsigned short* __restrict__ vb,
    const unsigned short* __restrict__ sr,
    const float* __restrict__ tdec, const float* __restrict__ tfirst,
    const float4* __restrict__ st, unsigned short* __restrict__ p)
{
    const int g = blockIdx.x * 256 + threadIdx.x;
    const int c = g & (C_ - 1);
    const int j = (g >> 10) & (NC - 1);
    const int b = g >> 14;
    const float w = -__expf(tdec[c]);
    const float u = tfirst[c];

    float aa = 0.f, bb = 0.f, pp = -1e38f;
    for (int i = 0; i < j; ++i) {
        const float4 s = st[((size_t)b * NC + i) * C_ + c];
        const float pdec = pp + w * (float)LCH;
        const float q  = fmaxf(pdec, s.z);
        const float eA = __expf(pdec - q);
        const float eB = __expf(s.z - q);
        aa = eA * aa + eB * s.x;
        bb = eA * bb + eB * s.y;
        pp = q;
    }

    const size_t base = ((size_t)(b * T_ + j * LCH)) * C_ + c;
    #pragma unroll 4
    for (int t = 0; t < LCH; ++t) {
        const size_t idx = base + (size_t)t * C_;
        const float kt = bf2f(kb[idx]);
        const float vt = bf2f(vb[idx]);
        const float ww = u + kt;
        const float qq = fmaxf(pp, ww);
        const float e1 = __expf(pp - qq);
        const float e2 = __expf(ww - qq);
        const float y  = (e1 * aa + e2 * vt) / (e1 * bb + e2);
        p[idx] = f2bf(bf2f(sr[idx]) * y);
        const float ww2 = pp + w;
        const float qq2 = fmaxf(ww2, kt);
        const float e1b = __expf(ww2 - qq2);
        const float e2b = __expf(kt - qq2);
        aa = e1b * aa + e2b * vt;
        bb = e1b * bb + e2b;
        pp = qq2;
    }
}

// ---------------------------------------------------------------------------
// Pipelined GEMM core: BM=BN=256, BK=64, 8 waves (2Mx4N), per-wave C=128x64
// (acc[8][4] 16x16 frags). LDS = 2 slots x (A 32K + B 32K) = 128 KiB.
// Zero-conflict swizzle (proven r2): 128B rows, block q of row r at q^(r&7);
// source pre-swizzled, LDS dest linear, read XOR'd.
//
// ONE barrier per K-tile. All LDS reads of a tile happen AFTER that tile's
// entry barrier (no cross-tile LDS prefetch -- that was r3's cross-wave race:
// vmcnt only proves the OWN wave's stages, but B/A rows are staged by ALL
// waves, so any read of a freshly staged slot must be {drain -> barrier}
// separated from the stage issue).
//
// Per tile t (read slot rs=t&1, stage t+1 into ns=rs^1):
//  F0: ds_read bc(8)+aP01(4) | SB0 | ds_read aQ23(4) | stage A(t+1)
//      -> lgkmcnt(4) [proves bc+aP, aQ stays in flight] -> MFMA rows 0,1
//  F1: ds_read aP45 | stage B(t+1) -> lgkmcnt(4) [proves aQ23] -> rows 2,3
//  F2: ds_read aQ67            -> lgkmcnt(4) [proves aP45] -> rows 4,5
//  F3: lgkmcnt(0) [proves aQ67 => all reads of rs retired: WAR-safe]
//      -> MFMA rows 6,7 -> vmcnt(0) [8 stages issued 2-3 phases ago: mostly
//      hidden] -> s_barrier.
// SB0 between read groups pins issue order so counted lgkm waits are exact.
// ---------------------------------------------------------------------------
static __device__ __forceinline__ void gemm_core256(
    const unsigned short* __restrict__ A, int lda,
    const unsigned short* __restrict__ Bw, int ldb,
    int K, int m0, int n0,
    unsigned short* As, unsigned short* Bs, f32x4 acc[8][4])
{
    const int tid  = threadIdx.x;
    const int l    = tid & 63;
    const int l16  = l & 15, quad = l >> 4;
    const int w    = tid >> 6;
    const int wm   = w >> 2, wn = w & 3;        // 2 x 4 wave grid

    // ---- staging source addressing (pre-swizzled global, linear LDS dest)
    const int sr_ = tid >> 3;                    // 0..63
    const int sb_ = (tid & 7) ^ (sr_ & 7);       // swizzled 16B source block
    const unsigned short* gA = A  + (size_t)(m0 + sr_) * lda + sb_ * 8;
    const unsigned short* gB = Bw + (size_t)(n0 + sr_) * ldb + sb_ * 8;

    auto stA = [&](int tt, int ss, int u) {
        GLDS16(gA + (size_t)u * 64 * lda + tt * 64, As + ss * 16384 + u * 4096 + w * 512);
    };
    auto stB = [&](int tt, int ss, int u) {
        GLDS16(gB + (size_t)u * 64 * ldb + tt * 64, Bs + ss * 16384 + u * 4096 + w * 512);
    };

    // ---- fragment read addressing: row = band + frag*16 + l16 (row&7=l16&7);
    // logical block = s*4+quad (K-step s), physical = logical ^ (l16&7).
    const int swz = l16 & 7;
    const unsigned short* aR = As + (wm * 128 + l16) * 64;
    const unsigned short* bR = Bs + (wn * 64  + l16) * 64;
    const int o0 = ((0 + quad) ^ swz) * 8;       // K-step 0
    const int o1 = ((4 + quad) ^ swz) * 8;       // K-step 1

    // ---- prologue: stage tile 0 -> slot 0, drain once
    stA(0, 0, 0); stA(0, 0, 1); stA(0, 0, 2); stA(0, 0, 3);
    stB(0, 0, 0); stB(0, 0, 1); stB(0, 0, 2); stB(0, 0, 3);
    asm volatile("s_waitcnt vmcnt(0)" ::: "memory");
    SB0();
    __builtin_amdgcn_s_barrier();
    SB0();

    const int NT = K >> 6;
    for (int t = 0; t < NT; ++t) {
        const int rs = t & 1, ns = rs ^ 1;
        const unsigned short* ab = aR + rs * 16384;
        const unsigned short* bb = bR + rs * 16384;
        const bool pf = (t + 1 < NT);
        bf16x8 bc0[4], bc1[4], aP0[2], aP1[2], aQ0[2], aQ1[2];

        // ===== F0 =====
        #pragma unroll
        for (int j = 0; j < 4; ++j) {
            bc0[j] = *(const bf16x8*)(bb + j * 1024 + o0);
            bc1[j] = *(const bf16x8*)(bb + j * 1024 + o1);
        }
        #pragma unroll
        for (int r = 0; r < 2; ++r) {
            aP0[r] = *(const bf16x8*)(ab + r * 1024 + o0);
            aP1[r] = *(const bf16x8*)(ab + r * 1024 + o1);
        }
        SB0();   // pin: the 12 reads above precede the 4 below
        #pragma unroll
        for (int r = 0; r < 2; ++r) {
            aQ0[r] = *(const bf16x8*)(ab + (2 + r) * 1024 + o0);
            aQ1[r] = *(const bf16x8*)(ab + (2 + r) * 1024 + o1);
        }
        if (pf) { stA(t + 1, ns, 0); stA(t + 1, ns, 1); stA(t + 1, ns, 2); stA(t + 1, ns, 3); }
        asm volatile("s_waitcnt lgkmcnt(4)" ::: "memory");
        SB0();
        __builtin_amdgcn_s_setprio(1);
        #pragma unroll
        for (int r = 0; r < 2; ++r)
            #pragma unroll
            for (int j = 0; j < 4; ++j) {
                acc[r][j] = MFMA_BF16(aP0[r], bc0[j], acc[r][j]);
                acc[r][j] = MFMA_BF16(aP1[r], bc1[j], acc[r][j]);
            }
        __builtin_amdgcn_s_setprio(0);
        SB0();

        // ===== F1 =====
        #pragma unroll
        for (int r = 0; r < 2; ++r) {
            aP0[r] = *(const bf16x8*)(ab + (4 + r) * 1024 + o0);
            aP1[r] = *(const bf16x8*)(ab + (4 + r) * 1024 + o1);
        }
        if (pf) { stB(t + 1, ns, 0); stB(t + 1, ns, 1); stB(t + 1, ns, 2); stB(t + 1, ns, 3); }
        asm volatile("s_waitcnt lgkmcnt(4)" ::: "memory");
        SB0();
        __builtin_amdgcn_s_setprio(1);
        #pragma unroll
        for (int r = 0; r < 2; ++r)
            #pragma unroll
            for (int j = 0; j < 4; ++j) {
                acc[2 + r][j] = MFMA_BF16(aQ0[r], bc0[j], acc[2 + r][j]);
                acc[2 + r][j] = MFMA_BF16(aQ1[r], bc1[j], acc[2 + r][j]);
            }
        __builtin_amdgcn_s_setprio(0);
        SB0();

        // ===== F2 =====
        #pragma unroll
        for (int r = 0; r < 2; ++r) {
            aQ0[r] = *(const bf16x8*)(ab + (6 + r) * 1024 + o0);
            aQ1[r] = *(const bf16x8*)(ab + (6 + r) * 1024 + o1);
        }
        asm volatile("s_waitcnt lgkmcnt(4)" ::: "memory");
        SB0();
        __builtin_amdgcn_s_setprio(1);
        #pragma unroll
        for (int r = 0; r < 2; ++r)
            #pragma unroll
            for (int j = 0; j < 4; ++j) {
                acc[4 + r][j] = MFMA_BF16(aP0[r], bc0[j], acc[4 + r][j]);
                acc[4 + r][j] = MFMA_BF16(aP1[r], bc1[j], acc[4 + r][j]);
            }
        __builtin_amdgcn_s_setprio(0);
        SB0();

        // ===== F3 =====
        asm volatile("s_waitcnt lgkmcnt(0)" ::: "memory");
        SB0();
        __builtin_amdgcn_s_setprio(1);
        #pragma unroll
        for (int r = 0; r < 2; ++r)
            #pragma unroll
            for (int j = 0; j < 4; ++j) {
                acc[6 + r][j] = MFMA_BF16(aQ0[r], bc0[j], acc[6 + r][j]);
                acc[6 + r][j] = MFMA_BF16(aQ1[r], bc1[j], acc[6 + r][j]);
            }
        __builtin_amdgcn_s_setprio(0);
        SB0();
        asm volatile("s_waitcnt vmcnt(0)" ::: "memory");   // tile t+1 fully staged
        SB0();
        __builtin_amdgcn_s_barrier();   // slot roles swap
        SB0();
    }
}

// Generic GEMM. EPI: 1 = sigmoid->bf16; 2 = resid + acc -> fp32;
//                3 = relu(acc)^2 -> bf16; 4 = outF += bf16(mul)*acc
template<int EPI>
__global__ __launch_bounds__(512, 1) void k_gemm(
    const unsigned short* __restrict__ A, int lda,
    const unsigned short* __restrict__ Bw, int ldb,
    int K, int N,
    float* __restrict__ outF, unsigned short* __restrict__ outH,
    const float* __restrict__ resid, const unsigned short* __restrict__ mul)
{
    __shared__ unsigned short As[2 * 16384];   // 64 KiB
    __shared__ unsigned short Bs[2 * 16384];   // 64 KiB
    f32x4 acc[8][4];
    const f32x4 zero = {0.f, 0.f, 0.f, 0.f};
    #pragma unroll
    for (int i = 0; i < 8; ++i)
        #pragma unroll
        for (int j = 0; j < 4; ++j) acc[i][j] = zero;

    const int m0 = blockIdx.x * 256, n0 = blockIdx.y * 256;
    gemm_core256(A, lda, Bw, ldb, K, m0, n0, As, Bs, acc);

    const int lane = threadIdx.x & 63, wave = threadIdx.x >> 6;
    const int quad = lane >> 4, l16 = lane & 15;
    const int wm = (wave >> 2) * 128, wn = (wave & 3) * 64;
    #pragma unroll
    for (int i = 0; i < 8; ++i) {
        const int rowb = m0 + wm + i * 16 + quad * 4;
        #pragma unroll
        for (int j = 0; j < 4; ++j) {
            const int col = n0 + wn + j * 16 + l16;
            #pragma unroll
            for (int r = 0; r < 4; ++r) {
                const size_t idx = (size_t)(rowb + r) * N + col;
                const float v = acc[i][j][r];
                if (EPI == 1)      outH[idx] = f2bf(1.f / (1.f + __expf(-v)));
                else if (EPI == 2) outF[idx] = resid[idx] + v;
                else if (EPI == 3) { const float z = v > 0.f ? v : 0.f; outH[idx] = f2bf(z * z); }
                else               outF[idx] = outF[idx] + bf2f(mul[idx]) * v;
            }
        }
    }
}

// Fused k/v/r projection: one dispatch vs packed [Wk;Wv;Wr] (N=3072).
// n-segment (n0>>10, uniform per block) selects BOTH the A input (xk/xv/xr)
// and the output (k->ok, v->ov, sigmoid(r)->orr). 256-tiles divide 1024.
__global__ __launch_bounds__(512, 1) void k_gemm_kvr(
    const unsigned short* __restrict__ xk, const unsigned short* __restrict__ xv,
    const unsigned short* __restrict__ xr,
    const unsigned short* __restrict__ W3,
    unsigned short* __restrict__ ok, unsigned short* __restrict__ ov,
    unsigned short* __restrict__ orr)
{
    __shared__ unsigned short As[2 * 16384];
    __shared__ unsigned short Bs[2 * 16384];
    f32x4 acc[8][4];
    const f32x4 zero = {0.f, 0.f, 0.f, 0.f};
    #pragma unroll
    for (int i = 0; i < 8; ++i)
        #pragma unroll
        for (int j = 0; j < 4; ++j) acc[i][j] = zero;

    const int m0 = blockIdx.x * 256, n0 = blockIdx.y * 256;
    const int seg = n0 >> 10;                       // 0=k 1=v 2=r
    const unsigned short* A = (seg == 0) ? xk : (seg == 1) ? xv : xr;
    unsigned short* outH    = (seg == 0) ? ok : (seg == 1) ? ov : orr;

    gemm_core256(A, C_, W3, C_, C_, m0, n0, As, Bs, acc);

    const int nl0 = n0 & (C_ - 1);
    const int lane = threadIdx.x & 63, wave = threadIdx.x >> 6;
    const int quad = lane >> 4, l16 = lane & 15;
    const int wm = (wave >> 2) * 128, wn = (wave & 3) * 64;
    #pragma unroll
    for (int i = 0; i < 8; ++i) {
        const int rowb = m0 + wm + i * 16 + quad * 4;
        #pragma unroll
        for (int j = 0; j < 4; ++j) {
            const int col = nl0 + wn + j * 16 + l16;
            #pragma unroll
            for (int r = 0; r < 4; ++r) {
                const size_t idx = (size_t)(rowb + r) * C_ + col;
                float v = acc[i][j][r];
                if (seg == 2) v = 1.f / (1.f + __expf(-v));
                outH[idx] = f2bf(v);
            }
        }
    }
}

// ---------------------------------------------------------------------------
// Workspace layout (peak 154 MB):
//   [0,32)MB    xk   -> WKV states (2MB) -> xk2
//   [32,64)     xv   -> p    -> tmp (FFN chunk)
//   [64,96)     xr   -> xr2
//   [96,128)    sr   -> s2
//   [128,154)   bf16 weights ([Wk;Wv;Wr] contiguous for fused GEMM)
// k,v (bf16, 32MB each) live in d_out until step 5 overwrites it.
// ---------------------------------------------------------------------------
extern "C" void kernel_launch(void* const* d_in, const int* in_sizes, int n_in,
                              void* d_out, int out_size, void* d_ws, size_t ws_size,
                              hipStream_t stream)
{
    const float* x      = (const float*)d_in[0];
    const float* ln1w   = (const float*)d_in[1];
    const float* ln1b   = (const float*)d_in[2];
    const float* ln2w   = (const float*)d_in[3];
    const float* ln2b   = (const float*)d_in[4];
    const float* atk    = (const float*)d_in[5];
    const float* atv    = (const float*)d_in[6];
    const float* atr    = (const float*)d_in[7];
    const float* tdec   = (const float*)d_in[8];
    const float* tfirst = (const float*)d_in[9];
    const float* Wk     = (const float*)d_in[10];
    const float* Wv     = (const float*)d_in[11];
    const float* Wr     = (const float*)d_in[12];
    const float* Wo     = (const float*)d_in[13];
    const float* ftk    = (const float*)d_in[14];
    const float* ftr    = (const float*)d_in[15];
    const float* Wkey   = (const float*)d_in[16];
    const float* Wrec   = (const float*)d_in[17];
    const float* Wval   = (const float*)d_in[18];
    float* out = (float*)d_out;

    char* ws = (char*)d_ws;
    const size_t MB = 1ull << 20;
    unsigned short* xk  = (unsigned short*)(ws + 0 * MB);
    unsigned short* xv  = (unsigned short*)(ws + 32 * MB);
    unsigned short* xr  = (unsigned short*)(ws + 64 * MB);
    unsigned short* sr  = (unsigned short*)(ws + 96 * MB);
    unsigned short* wb  = (unsigned short*)(ws + 128 * MB);
    float4* states      = (float4*)(ws + 0 * MB);   // 2MB, xk dead after kvr GEMM
    unsigned short* p   = xv;   // p overwrites xv (dead after kvr GEMM)
    unsigned short* xk2 = xk;
    unsigned short* xr2 = xr;
    unsigned short* s2  = sr;
    unsigned short* tmp = xv;   // FFN chunk buffer (p dead after Wo-GEMM)
    unsigned short* kb  = (unsigned short*)d_out;             // 32MB
    unsigned short* vb  = (unsigned short*)d_out + (32*MB/2); // 32MB

    unsigned short* W3_b   = wb;                   // [Wk;Wv;Wr] 3072x1024
    unsigned short* Wo_b   = wb + 3 * (1u << 20);
    unsigned short* Wrec_b = wb + 4 * (1u << 20);
    unsigned short* Wkey_b = wb + 5 * (1u << 20);
    unsigned short* Wval_b = wb + 9 * (1u << 20);

    // 1) weights -> bf16
    WSrc wsrc; wsrc.p[0]=Wk; wsrc.p[1]=Wv; wsrc.p[2]=Wr; wsrc.p[3]=Wo;
    wsrc.p[4]=Wrec; wsrc.p[5]=Wkey; wsrc.p[6]=Wval;
    k_convert<<<dim3(13312), dim3(256), 0, stream>>>(wsrc, wb);

    // 2) LN1 + time-shift mix -> xk, xv, xr (bf16)
    k_ln_mix<1><<<dim3(M_), dim3(256), 0, stream>>>(x, ln1w, ln1b, atk, atv, atr, xk, xv, xr);

    // 3) fused k/v/r projections (N=3072): k->kb, v->vb, sigmoid(r)->sr
    k_gemm_kvr<<<dim3(64, 12), dim3(512), 0, stream>>>(xk, xv, xr, W3_b, kb, vb, sr);

    // 4) WKV: chunk-parallel scan
    k_wkv_local<<<dim3(512), dim3(256), 0, stream>>>(kb, vb, tdec, states);
    k_wkv_scan<<<dim3(512), dim3(256), 0, stream>>>(kb, vb, sr, tdec, tfirst, states, p);

    // 5) x1 = x + p @ Wo^T -> d_out (fp32)
    k_gemm<2><<<dim3(64, 4), dim3(512), 0, stream>>>(p, 1024, Wo_b, 1024, 1024, 1024, out, (unsigned short*)nullptr, x, (const unsigned short*)nullptr);

    // 6) LN2 + time-shift mix -> xk2, xr2 (bf16)
    k_ln_mix<0><<<dim3(M_), dim3(256), 0, stream>>>(out, ln2w, ln2b, ftk, (const float*)nullptr, ftr, xk2, (unsigned short*)nullptr, xr2);

    // 7) s2 = sigmoid(xr2 @ Wrec^T) (bf16)
    k_gemm<1><<<dim3(64, 4), dim3(512), 0, stream>>>(xr2, 1024, Wrec_b, 1024, 1024, 1024, (float*)nullptr, s2, (const float*)nullptr, (const unsigned short*)nullptr);

    // 8) FFN chunked over F (4 x 1024): out += s2 * (relu(xk2@Wkey_f^T)^2 @ Wval_f^T)
    for (int f = 0; f < 4; ++f) {
        const unsigned short* WkeyF = Wkey_b + (size_t)f * 1024 * 1024;
        const unsigned short* WvalF = Wval_b + (size_t)f * 1024;
        k_gemm<3><<<dim3(64, 4), dim3(512), 0, stream>>>(xk2, 1024, WkeyF, 1024, 1024, 1024, (float*)nullptr, tmp, (const float*)nullptr, (const unsigned short*)nullptr);
        k_gemm<4><<<dim3(64, 4), dim3(512), 0, stream>>>(tmp, 1024, WvalF, 4096, 1024, 1024, out, (unsigned short*)nullptr, (const float*)nullptr, s2);
    }
}

// Round 5
// 866.530 us; speedup vs baseline: 1.1109x; 1.1109x over previous
//
#include <hip/hip_runtime.h>
#include <stdint.h>

// RWKV-4 block: B=8, T=2048, C=1024, DIM_FFN=4096, fp32 in/out, bf16 MFMA internally.
#define B_ 8
#define T_ 2048
#define C_ 1024
#define F_ 4096
#define M_ (B_*T_)   // 16384 rows
#define NC 16        // WKV chunks per sequence
#define LCH (T_/NC)  // 128 steps per chunk

typedef __attribute__((ext_vector_type(8))) short bf16x8;   // MFMA A/B frag (4 VGPRs)
typedef __attribute__((ext_vector_type(4))) float f32x4;    // MFMA C/D frag

static __device__ __forceinline__ unsigned short f2bf(float f) {
    union { float f; unsigned u; } v; v.f = f;
    unsigned r = v.u + 0x7fffu + ((v.u >> 16) & 1u);  // RNE
    return (unsigned short)(r >> 16);
}
static __device__ __forceinline__ float bf2f(unsigned short h) {
    union { unsigned u; float f; } v; v.u = ((unsigned)h) << 16;
    return v.f;
}

// async global->LDS, 16B/lane, wave-uniform LDS base + lane*16 (m97 pattern)
#define GLDS16(gp, lp) __builtin_amdgcn_global_load_lds( \
    (const __attribute__((address_space(1))) unsigned int*)(gp), \
    (__attribute__((address_space(3))) unsigned int*)(lp), 16, 0, 0)

#define SB0() __builtin_amdgcn_sched_barrier(0)
#define MFMA_BF16(a, b, c) __builtin_amdgcn_mfma_f32_16x16x32_bf16((a), (b), (c), 0, 0, 0)

// ---------------------------------------------------------------------------
// Weight conversion fp32 -> bf16 into one packed ws region (13M elems, 26MB).
// dst element layout: [Wk 1M][Wv 1M][Wr 1M][Wo 1M][Wrec 1M][Wkey 4M][Wval 4M]
// ---------------------------------------------------------------------------
struct WSrc { const float* p[7]; };

__global__ __launch_bounds__(256) void k_convert(WSrc w, unsigned short* __restrict__ dst) {
    size_t e = ((size_t)blockIdx.x * 256 + threadIdx.x) * 4;
    int seg = (int)(e >> 20);
    const float* s; size_t off;
    if (seg < 5)      { s = w.p[seg]; off = e - ((size_t)seg << 20); }
    else if (seg < 9) { s = w.p[5];   off = e - (5ull << 20); }
    else              { s = w.p[6];   off = e - (9ull << 20); }
    float4 v = *(const float4*)(s + off);
    ushort4 o;
    o.x = f2bf(v.x); o.y = f2bf(v.y); o.z = f2bf(v.z); o.w = f2bf(v.w);
    *(ushort4*)(dst + e) = o;
}

// ---------------------------------------------------------------------------
// Fused LayerNorm + time_shift + token-mix. One block per row m = b*T+t.
// ---------------------------------------------------------------------------
template<int THREE>
__global__ __launch_bounds__(256) void k_ln_mix(
    const float* __restrict__ xin, const float* __restrict__ lw, const float* __restrict__ lb,
    const float* __restrict__ tk, const float* __restrict__ tv, const float* __restrict__ tr,
    unsigned short* __restrict__ ok, unsigned short* __restrict__ ov, unsigned short* __restrict__ orr)
{
    __shared__ float sred[4][4];
    const int m = blockIdx.x;
    const int t = m & (T_ - 1);
    const int tid = threadIdx.x;
    const int col0 = tid * 4;

    const float4 xc = *(const float4*)(xin + (size_t)m * C_ + col0);
    float4 xp = make_float4(0.f, 0.f, 0.f, 0.f);
    if (t > 0) xp = *(const float4*)(xin + (size_t)(m - 1) * C_ + col0);

    float s1 = xc.x + xc.y + xc.z + xc.w;
    float s2 = xc.x*xc.x + xc.y*xc.y + xc.z*xc.z + xc.w*xc.w;
    float s3 = xp.x + xp.y + xp.z + xp.w;
    float s4 = xp.x*xp.x + xp.y*xp.y + xp.z*xp.z + xp.w*xp.w;
    #pragma unroll
    for (int off = 32; off > 0; off >>= 1) {
        s1 += __shfl_down(s1, off);
        s2 += __shfl_down(s2, off);
        s3 += __shfl_down(s3, off);
        s4 += __shfl_down(s4, off);
    }
    const int wave = tid >> 6, lane = tid & 63;
    if (lane == 0) { sred[0][wave]=s1; sred[1][wave]=s2; sred[2][wave]=s3; sred[3][wave]=s4; }
    __syncthreads();
    const float S1 = sred[0][0]+sred[0][1]+sred[0][2]+sred[0][3];
    const float S2 = sred[1][0]+sred[1][1]+sred[1][2]+sred[1][3];
    const float S3 = sred[2][0]+sred[2][1]+sred[2][2]+sred[2][3];
    const float S4 = sred[3][0]+sred[3][1]+sred[3][2]+sred[3][3];

    const float inv = 1.0f / (float)C_;
    const float muc = S1 * inv;
    const float rc  = rsqrtf(S2 * inv - muc * muc + 1e-5f);
    const float mup = S3 * inv;
    const float rp  = rsqrtf(S4 * inv - mup * mup + 1e-5f);

    const float xcv[4] = {xc.x, xc.y, xc.z, xc.w};
    const float xpv[4] = {xp.x, xp.y, xp.z, xp.w};
    unsigned short rk[4], rv[4], rr[4];
    #pragma unroll
    for (int i = 0; i < 4; ++i) {
        const int col = col0 + i;
        const float w_ = lw[col], b_ = lb[col];
        const float h  = (xcv[i] - muc) * rc * w_ + b_;
        const float hh = (t > 0) ? (xpv[i] - mup) * rp * w_ + b_ : 0.f;
        const float ak = tk[col];
        rk[i] = f2bf(h * ak + hh * (1.f - ak));
        if (THREE) { const float av = tv[col]; rv[i] = f2bf(h * av + hh * (1.f - av)); }
        const float ar = tr[col];
        rr[i] = f2bf(h * ar + hh * (1.f - ar));
    }
    const size_t o = (size_t)m * C_ + col0;
    ushort4 u;
    u.x = rk[0]; u.y = rk[1]; u.z = rk[2]; u.w = rk[3];
    *(ushort4*)(ok + o) = u;
    if (THREE) {
        u.x = rv[0]; u.y = rv[1]; u.z = rv[2]; u.w = rv[3];
        *(ushort4*)(ov + o) = u;
    }
    u.x = rr[0]; u.y = rr[1]; u.z = rr[2]; u.w = rr[3];
    *(ushort4*)(orr + o) = u;
}

// ---------------------------------------------------------------------------
// WKV pass A: per (b,c,chunk) local state recurrence from zero init.
// ---------------------------------------------------------------------------
__global__ __launch_bounds__(256) void k_wkv_local(
    const unsigned short* __restrict__ kb, const unsigned short* __restrict__ vb,
    const float* __restrict__ tdec, float4* __restrict__ st)
{
    const int g = blockIdx.x * 256 + threadIdx.x;   // 0..131071
    const int c = g & (C_ - 1);
    const int j = (g >> 10) & (NC - 1);
    const int b = g >> 14;
    const float w = -__expf(tdec[c]);
    float aa = 0.f, bb = 0.f, pp = -1e38f;
    const size_t base = ((size_t)(b * T_ + j * LCH)) * C_ + c;
    #pragma unroll 4
    for (int t = 0; t < LCH; ++t) {
        const float kt = bf2f(kb[base + (size_t)t * C_]);
        const float vt = bf2f(vb[base + (size_t)t * C_]);
        const float ww2 = pp + w;
        const float qq2 = fmaxf(ww2, kt);
        const float e1b = __expf(ww2 - qq2);
        const float e2b = __expf(kt - qq2);
        aa = e1b * aa + e2b * vt;
        bb = e1b * bb + e2b;
        pp = qq2;
    }
    st[((size_t)b * NC + j) * C_ + c] = make_float4(aa, bb, pp, 0.f);
}

// ---------------------------------------------------------------------------
// WKV pass C: combine preceding chunk states, replay chunk computing p=sr*y.
// ---------------------------------------------------------------------------
__global__ __launch_bounds__(256) void k_wkv_scan(
    const unsigned short* __restrict__ kb, const unsigned short* __restrict__ vb,
    const unsigned short* __restrict__ sr,
    const float* __restrict__ tdec, const float* __restrict__ tfirst,
    const float4* __restrict__ st, unsigned short* __restrict__ p)
{
    const int g = blockIdx.x * 256 + threadIdx.x;
    const int c = g & (C_ - 1);
    const int j = (g >> 10) & (NC - 1);
    const int b = g >> 14;
    const float w = -__expf(tdec[c]);
    const float u = tfirst[c];

    float aa = 0.f, bb = 0.f, pp = -1e38f;
    for (int i = 0; i < j; ++i) {
        const float4 s = st[((size_t)b * NC + i) * C_ + c];
        const float pdec = pp + w * (float)LCH;
        const float q  = fmaxf(pdec, s.z);
        const float eA = __expf(pdec - q);
        const float eB = __expf(s.z - q);
        aa = eA * aa + eB * s.x;
        bb = eA * bb + eB * s.y;
        pp = q;
    }

    const size_t base = ((size_t)(b * T_ + j * LCH)) * C_ + c;
    #pragma unroll 4
    for (int t = 0; t < LCH; ++t) {
        const size_t idx = base + (size_t)t * C_;
        const float kt = bf2f(kb[idx]);
        const float vt = bf2f(vb[idx]);
        const float ww = u + kt;
        const float qq = fmaxf(pp, ww);
        const float e1 = __expf(pp - qq);
        const float e2 = __expf(ww - qq);
        const float y  = (e1 * aa + e2 * vt) / (e1 * bb + e2);
        p[idx] = f2bf(bf2f(sr[idx]) * y);
        const float ww2 = pp + w;
        const float qq2 = fmaxf(ww2, kt);
        const float e1b = __expf(ww2 - qq2);
        const float e2b = __expf(kt - qq2);
        aa = e1b * aa + e2b * vt;
        bb = e1b * bb + e2b;
        pp = qq2;
    }
}

// ---------------------------------------------------------------------------
// 4-phase/K-tile GEMM core (verified r2 schedule, best measured):
// BM=BN=256, BK=64, 8 waves (2Mx4N), per-wave C = 128x64 (acc[8][4]).
// LDS = 2 slots x (A 32K + B 32K) = 128 KiB. 1 block/CU.
// Zero-conflict swizzle: 128B rows, 16B block q of row r at q^(r&7);
// pre-swizzled global source + linear LDS dest + XOR'd read (rule #21).
// Per K-tile t (slot t&1), 4 phases, stage tile t+1 into (t&1)^1:
//   F0: read B(8)+A01(4) | stage A(t+1) {0,2} | 16 MFMA
//   F1: read A23          | stage B(t+1) all   | 16 MFMA -> vmcnt(6)
//   F2: read A45          | stage A(t+1) {1,3} | 16 MFMA
//   F3: read A67          |                    | 16 MFMA -> vmcnt(2)
// Each phase: [ds_read; stage; barrier; lgkmcnt(0); setprio(1); MFMA;
// setprio(0); (counted vmcnt); barrier]. Counted vmcnt never drains to 0.
// ---------------------------------------------------------------------------
static __device__ __forceinline__ void gemm_core256(
    const unsigned short* __restrict__ A, int lda,
    const unsigned short* __restrict__ Bw, int ldb,
    int K, int m0, int n0,
    unsigned short* As, unsigned short* Bs, f32x4 acc[8][4])
{
    const int tid  = threadIdx.x;
    const int l    = tid & 63;
    const int l16  = l & 15, quad = l >> 4;
    const int w    = tid >> 6;
    const int wm   = w >> 2, wn = w & 3;        // 2 x 4 wave grid

    // ---- staging source addressing (pre-swizzled global, linear LDS dest)
    const int sr_ = tid >> 3;                    // 0..63
    const int sb_ = (tid & 7) ^ (sr_ & 7);       // swizzled 16B source block
    const unsigned short* gA = A  + (size_t)(m0 + sr_) * lda + sb_ * 8;
    const unsigned short* gB = Bw + (size_t)(n0 + sr_) * ldb + sb_ * 8;

    auto stA = [&](int tt, int ss, int u) {
        GLDS16(gA + (size_t)u * 64 * lda + tt * 64, As + ss * 16384 + u * 4096 + w * 512);
    };
    auto stB = [&](int tt, int ss, int u) {
        GLDS16(gB + (size_t)u * 64 * ldb + tt * 64, Bs + ss * 16384 + u * 4096 + w * 512);
    };

    // ---- fragment read addressing: row = band + frag*16 + l16 (row&7=l16&7);
    // logical block = s*4+quad (K-step s), physical = logical ^ (l16&7).
    const int swz = l16 & 7;
    const unsigned short* aR = As + (wm * 128 + l16) * 64;
    const unsigned short* bR = Bs + (wn * 64  + l16) * 64;
    const int o0 = ((0 + quad) ^ swz) * 8;       // K-step 0
    const int o1 = ((4 + quad) ^ swz) * 8;       // K-step 1

    // ---- prologue: stage tile 0 fully, one-time drain
    stA(0, 0, 0); stA(0, 0, 2);
    stB(0, 0, 0); stB(0, 0, 1); stB(0, 0, 2); stB(0, 0, 3);
    stA(0, 0, 1); stA(0, 0, 3);
    asm volatile("s_waitcnt vmcnt(0)" ::: "memory");
    SB0();
    __builtin_amdgcn_s_barrier();
    SB0();

    const int NT = K >> 6;
    for (int t = 0; t < NT; ++t) {
        const int rs = t & 1, ns = rs ^ 1;
        const unsigned short* ab = aR + rs * 16384;
        const unsigned short* bb = bR + rs * 16384;
        const bool pf = (t + 1 < NT);
        bf16x8 b0[4], b1[4];

        // ===== F0: all B frags + A frags 0,1; stage A(t+1) units {0,2} =====
        {
            bf16x8 a0[2], a1[2];
            #pragma unroll
            for (int j = 0; j < 4; ++j) {
                b0[j] = *(const bf16x8*)(bb + j * 1024 + o0);
                b1[j] = *(const bf16x8*)(bb + j * 1024 + o1);
            }
            #pragma unroll
            for (int i = 0; i < 2; ++i) {
                a0[i] = *(const bf16x8*)(ab + i * 1024 + o0);
                a1[i] = *(const bf16x8*)(ab + i * 1024 + o1);
            }
            if (pf) { stA(t + 1, ns, 0); stA(t + 1, ns, 2); }
            SB0();
            __builtin_amdgcn_s_barrier();
            asm volatile("s_waitcnt lgkmcnt(0)" ::: "memory");
            SB0();
            __builtin_amdgcn_s_setprio(1);
            #pragma unroll
            for (int i = 0; i < 2; ++i)
                #pragma unroll
                for (int j = 0; j < 4; ++j) {
                    acc[i][j] = MFMA_BF16(a0[i], b0[j], acc[i][j]);
                    acc[i][j] = MFMA_BF16(a1[i], b1[j], acc[i][j]);
                }
            __builtin_amdgcn_s_setprio(0);
            SB0();
            __builtin_amdgcn_s_barrier();
            SB0();
        }

        // ===== F1: A frags 2,3; stage B(t+1) all; vmcnt(6) proves A(t) h1 =====
        {
            bf16x8 a0[2], a1[2];
            #pragma unroll
            for (int i = 0; i < 2; ++i) {
                a0[i] = *(const bf16x8*)(ab + (2 + i) * 1024 + o0);
                a1[i] = *(const bf16x8*)(ab + (2 + i) * 1024 + o1);
            }
            if (pf) { stB(t + 1, ns, 0); stB(t + 1, ns, 1); stB(t + 1, ns, 2); stB(t + 1, ns, 3); }
            SB0();
            __builtin_amdgcn_s_barrier();
            asm volatile("s_waitcnt lgkmcnt(0)" ::: "memory");
            SB0();
            __builtin_amdgcn_s_setprio(1);
            #pragma unroll
            for (int i = 0; i < 2; ++i)
                #pragma unroll
                for (int j = 0; j < 4; ++j) {
                    acc[2 + i][j] = MFMA_BF16(a0[i], b0[j], acc[2 + i][j]);
                    acc[2 + i][j] = MFMA_BF16(a1[i], b1[j], acc[2 + i][j]);
                }
            __builtin_amdgcn_s_setprio(0);
            asm volatile("s_waitcnt vmcnt(6)" ::: "memory");
            SB0();
            __builtin_amdgcn_s_barrier();
            SB0();
        }

        // ===== F2: A frags 4,5; stage A(t+1) units {1,3} =====
        {
            bf16x8 a0[2], a1[2];
            #pragma unroll
            for (int i = 0; i < 2; ++i) {
                a0[i] = *(const bf16x8*)(ab + (4 + i) * 1024 + o0);
                a1[i] = *(const bf16x8*)(ab + (4 + i) * 1024 + o1);
            }
            if (pf) { stA(t + 1, ns, 1); stA(t + 1, ns, 3); }
            SB0();
            __builtin_amdgcn_s_barrier();
            asm volatile("s_waitcnt lgkmcnt(0)" ::: "memory");
            SB0();
            __builtin_amdgcn_s_setprio(1);
            #pragma unroll
            for (int i = 0; i < 2; ++i)
                #pragma unroll
                for (int j = 0; j < 4; ++j) {
                    acc[4 + i][j] = MFMA_BF16(a0[i], b0[j], acc[4 + i][j]);
                    acc[4 + i][j] = MFMA_BF16(a1[i], b1[j], acc[4 + i][j]);
                }
            __builtin_amdgcn_s_setprio(0);
            SB0();
            __builtin_amdgcn_s_barrier();
            SB0();
        }

        // ===== F3: A frags 6,7; vmcnt(2) proves A(t+1) h0 + B(t+1) =====
        {
            bf16x8 a0[2], a1[2];
            #pragma unroll
            for (int i = 0; i < 2; ++i) {
                a0[i] = *(const bf16x8*)(ab + (6 + i) * 1024 + o0);
                a1[i] = *(const bf16x8*)(ab + (6 + i) * 1024 + o1);
            }
            SB0();
            __builtin_amdgcn_s_barrier();
            asm volatile("s_waitcnt lgkmcnt(0)" ::: "memory");
            SB0();
            __builtin_amdgcn_s_setprio(1);
            #pragma unroll
            for (int i = 0; i < 2; ++i)
                #pragma unroll
                for (int j = 0; j < 4; ++j) {
                    acc[6 + i][j] = MFMA_BF16(a0[i], b0[j], acc[6 + i][j]);
                    acc[6 + i][j] = MFMA_BF16(a1[i], b1[j], acc[6 + i][j]);
                }
            __builtin_amdgcn_s_setprio(0);
            asm volatile("s_waitcnt vmcnt(2)" ::: "memory");
            SB0();
            __builtin_amdgcn_s_barrier();
            SB0();
        }
    }
}

// Generic GEMM. EPI: 1 = sigmoid->bf16; 2 = resid + acc -> fp32;
//                3 = relu(acc)^2 -> bf16; 4 = outF += bf16(mul)*acc
template<int EPI>
__global__ __launch_bounds__(512, 1) void k_gemm(
    const unsigned short* __restrict__ A, int lda,
    const unsigned short* __restrict__ Bw, int ldb,
    int K, int N,
    float* __restrict__ outF, unsigned short* __restrict__ outH,
    const float* __restrict__ resid, const unsigned short* __restrict__ mul)
{
    __shared__ unsigned short As[2 * 16384];   // 64 KiB
    __shared__ unsigned short Bs[2 * 16384];   // 64 KiB
    f32x4 acc[8][4];
    const f32x4 zero = {0.f, 0.f, 0.f, 0.f};
    #pragma unroll
    for (int i = 0; i < 8; ++i)
        #pragma unroll
        for (int j = 0; j < 4; ++j) acc[i][j] = zero;

    const int m0 = blockIdx.x * 256, n0 = blockIdx.y * 256;
    gemm_core256(A, lda, Bw, ldb, K, m0, n0, As, Bs, acc);

    const int lane = threadIdx.x & 63, wave = threadIdx.x >> 6;
    const int quad = lane >> 4, l16 = lane & 15;
    const int wm = (wave >> 2) * 128, wn = (wave & 3) * 64;
    #pragma unroll
    for (int i = 0; i < 8; ++i) {
        const int rowb = m0 + wm + i * 16 + quad * 4;
        #pragma unroll
        for (int j = 0; j < 4; ++j) {
            const int col = n0 + wn + j * 16 + l16;
            #pragma unroll
            for (int r = 0; r < 4; ++r) {
                const size_t idx = (size_t)(rowb + r) * N + col;
                const float v = acc[i][j][r];
                if (EPI == 1)      outH[idx] = f2bf(1.f / (1.f + __expf(-v)));
                else if (EPI == 2) outF[idx] = resid[idx] + v;
                else if (EPI == 3) { const float z = v > 0.f ? v : 0.f; outH[idx] = f2bf(z * z); }
                else               outF[idx] = outF[idx] + bf2f(mul[idx]) * v;
            }
        }
    }
}

// Fused k/v/r projection: one dispatch vs packed [Wk;Wv;Wr] (N=3072).
// n-segment (n0>>10, uniform per block) selects BOTH the A input (xk/xv/xr)
// and the output (k->ok, v->ov, sigmoid(r)->orr). 256-tiles divide 1024.
__global__ __launch_bounds__(512, 1) void k_gemm_kvr(
    const unsigned short* __restrict__ xk, const unsigned short* __restrict__ xv,
    const unsigned short* __restrict__ xr,
    const unsigned short* __restrict__ W3,
    unsigned short* __restrict__ ok, unsigned short* __restrict__ ov,
    unsigned short* __restrict__ orr)
{
    __shared__ unsigned short As[2 * 16384];
    __shared__ unsigned short Bs[2 * 16384];
    f32x4 acc[8][4];
    const f32x4 zero = {0.f, 0.f, 0.f, 0.f};
    #pragma unroll
    for (int i = 0; i < 8; ++i)
        #pragma unroll
        for (int j = 0; j < 4; ++j) acc[i][j] = zero;

    const int m0 = blockIdx.x * 256, n0 = blockIdx.y * 256;
    const int seg = n0 >> 10;                       // 0=k 1=v 2=r
    const unsigned short* A = (seg == 0) ? xk : (seg == 1) ? xv : xr;
    unsigned short* outH    = (seg == 0) ? ok : (seg == 1) ? ov : orr;

    gemm_core256(A, C_, W3, C_, C_, m0, n0, As, Bs, acc);

    const int nl0 = n0 & (C_ - 1);
    const int lane = threadIdx.x & 63, wave = threadIdx.x >> 6;
    const int quad = lane >> 4, l16 = lane & 15;
    const int wm = (wave >> 2) * 128, wn = (wave & 3) * 64;
    #pragma unroll
    for (int i = 0; i < 8; ++i) {
        const int rowb = m0 + wm + i * 16 + quad * 4;
        #pragma unroll
        for (int j = 0; j < 4; ++j) {
            const int col = nl0 + wn + j * 16 + l16;
            #pragma unroll
            for (int r = 0; r < 4; ++r) {
                const size_t idx = (size_t)(rowb + r) * C_ + col;
                float v = acc[i][j][r];
                if (seg == 2) v = 1.f / (1.f + __expf(-v));
                outH[idx] = f2bf(v);
            }
        }
    }
}

// ---------------------------------------------------------------------------
// Workspace layout (peak 154 MB):
//   [0,32)MB    xk   -> WKV states (2MB) -> xk2
//   [32,64)     xv   -> p (Wo input)     -> s2
//   [64,96)     xr   -> kk[0:32MB)
//   [96,128)    sr   -> xr2              -> kk[32:64MB)
//   [128,154)   bf16 weights ([Wk;Wv;Wr] contiguous for fused GEMM)
// k,v (bf16, 32MB each) live in d_out until step 5 overwrites it.
// FFN runs in 2 chunks of F=2048 through the 64MB kk buffer at [64,128):
// halves the fp32-out read-modify-write traffic (640 -> 320 MB) and the
// dispatch count (8 -> 4). xr2 ([96,128)) is dead after the Wrec GEMM,
// so kk may overwrite it from the first key-GEMM on.
// ---------------------------------------------------------------------------
extern "C" void kernel_launch(void* const* d_in, const int* in_sizes, int n_in,
                              void* d_out, int out_size, void* d_ws, size_t ws_size,
                              hipStream_t stream)
{
    const float* x      = (const float*)d_in[0];
    const float* ln1w   = (const float*)d_in[1];
    const float* ln1b   = (const float*)d_in[2];
    const float* ln2w   = (const float*)d_in[3];
    const float* ln2b   = (const float*)d_in[4];
    const float* atk    = (const float*)d_in[5];
    const float* atv    = (const float*)d_in[6];
    const float* atr    = (const float*)d_in[7];
    const float* tdec   = (const float*)d_in[8];
    const float* tfirst = (const float*)d_in[9];
    const float* Wk     = (const float*)d_in[10];
    const float* Wv     = (const float*)d_in[11];
    const float* Wr     = (const float*)d_in[12];
    const float* Wo     = (const float*)d_in[13];
    const float* ftk    = (const float*)d_in[14];
    const float* ftr    = (const float*)d_in[15];
    const float* Wkey   = (const float*)d_in[16];
    const float* Wrec   = (const float*)d_in[17];
    const float* Wval   = (const float*)d_in[18];
    float* out = (float*)d_out;

    char* ws = (char*)d_ws;
    const size_t MB = 1ull << 20;
    unsigned short* xk  = (unsigned short*)(ws + 0 * MB);
    unsigned short* xv  = (unsigned short*)(ws + 32 * MB);
    unsigned short* xr  = (unsigned short*)(ws + 64 * MB);
    unsigned short* sr  = (unsigned short*)(ws + 96 * MB);
    unsigned short* wb  = (unsigned short*)(ws + 128 * MB);
    float4* states      = (float4*)(ws + 0 * MB);   // 2MB, xk dead after kvr GEMM
    unsigned short* p   = xv;   // p overwrites xv (dead after kvr GEMM)
    unsigned short* xk2 = xk;                             // [0,32)
    unsigned short* xr2 = (unsigned short*)(ws + 96 * MB); // [96,128), sr dead after wkv_scan
    unsigned short* s2  = (unsigned short*)(ws + 32 * MB); // [32,64), p dead after Wo GEMM
    unsigned short* kk  = (unsigned short*)(ws + 64 * MB); // [64,128), 64MB: 16384 x 2048 bf16
    unsigned short* kb  = (unsigned short*)d_out;             // 32MB
    unsigned short* vb  = (unsigned short*)d_out + (32*MB/2); // 32MB

    unsigned short* W3_b   = wb;                   // [Wk;Wv;Wr] 3072x1024
    unsigned short* Wo_b   = wb + 3 * (1u << 20);
    unsigned short* Wrec_b = wb + 4 * (1u << 20);
    unsigned short* Wkey_b = wb + 5 * (1u << 20);
    unsigned short* Wval_b = wb + 9 * (1u << 20);

    // 1) weights -> bf16
    WSrc wsrc; wsrc.p[0]=Wk; wsrc.p[1]=Wv; wsrc.p[2]=Wr; wsrc.p[3]=Wo;
    wsrc.p[4]=Wrec; wsrc.p[5]=Wkey; wsrc.p[6]=Wval;
    k_convert<<<dim3(13312), dim3(256), 0, stream>>>(wsrc, wb);

    // 2) LN1 + time-shift mix -> xk, xv, xr (bf16)
    k_ln_mix<1><<<dim3(M_), dim3(256), 0, stream>>>(x, ln1w, ln1b, atk, atv, atr, xk, xv, xr);

    // 3) fused k/v/r projections (N=3072): k->kb, v->vb, sigmoid(r)->sr
    k_gemm_kvr<<<dim3(64, 12), dim3(512), 0, stream>>>(xk, xv, xr, W3_b, kb, vb, sr);

    // 4) WKV: chunk-parallel scan
    k_wkv_local<<<dim3(512), dim3(256), 0, stream>>>(kb, vb, tdec, states);
    k_wkv_scan<<<dim3(512), dim3(256), 0, stream>>>(kb, vb, sr, tdec, tfirst, states, p);

    // 5) x1 = x + p @ Wo^T -> d_out (fp32)
    k_gemm<2><<<dim3(64, 4), dim3(512), 0, stream>>>(p, 1024, Wo_b, 1024, 1024, 1024, out, (unsigned short*)nullptr, x, (const unsigned short*)nullptr);

    // 6) LN2 + time-shift mix -> xk2 [0,32), xr2 [96,128) (bf16)
    k_ln_mix<0><<<dim3(M_), dim3(256), 0, stream>>>(out, ln2w, ln2b, ftk, (const float*)nullptr, ftr, xk2, (unsigned short*)nullptr, xr2);

    // 7) s2 = sigmoid(xr2 @ Wrec^T) (bf16) -> [32,64); frees xr2 region
    k_gemm<1><<<dim3(64, 4), dim3(512), 0, stream>>>(xr2, 1024, Wrec_b, 1024, 1024, 1024, (float*)nullptr, s2, (const float*)nullptr, (const unsigned short*)nullptr);

    // 8) FFN in 2 chunks of F=2048: kk = relu(xk2@Wkey_c^T)^2 (N=2048),
    //    then out += s2 * (kk @ Wval_c^T) (K=2048)
    for (int c = 0; c < 2; ++c) {
        const unsigned short* WkeyC = Wkey_b + (size_t)c * 2048 * 1024;
        const unsigned short* WvalC = Wval_b + (size_t)c * 2048;
        k_gemm<3><<<dim3(64, 8), dim3(512), 0, stream>>>(xk2, 1024, WkeyC, 1024, 1024, 2048, (float*)nullptr, kk, (const float*)nullptr, (const unsigned short*)nullptr);
        k_gemm<4><<<dim3(64, 4), dim3(512), 0, stream>>>(kk, 2048, WvalC, 4096, 2048, 1024, out, (unsigned short*)nullptr, (const float*)nullptr, s2);
    }
}

// Round 6
// 851.065 us; speedup vs baseline: 1.1311x; 1.0182x over previous
//
#include <hip/hip_runtime.h>
#include <stdint.h>

// RWKV-4 block: B=8, T=2048, C=1024, DIM_FFN=4096, fp32 in/out, bf16 MFMA internally.
#define B_ 8
#define T_ 2048
#define C_ 1024
#define F_ 4096
#define M_ (B_*T_)   // 16384 rows
#define NC 16        // WKV chunks per sequence
#define LCH (T_/NC)  // 128 steps per chunk

typedef __attribute__((ext_vector_type(8))) short bf16x8;   // MFMA A/B frag (4 VGPRs)
typedef __attribute__((ext_vector_type(4))) float f32x4;    // MFMA C/D frag

static __device__ __forceinline__ unsigned short f2bf(float f) {
    union { float f; unsigned u; } v; v.f = f;
    unsigned r = v.u + 0x7fffu + ((v.u >> 16) & 1u);  // RNE
    return (unsigned short)(r >> 16);
}
static __device__ __forceinline__ float bf2f(unsigned short h) {
    union { unsigned u; float f; } v; v.u = ((unsigned)h) << 16;
    return v.f;
}

// async global->LDS, 16B/lane, wave-uniform LDS base + lane*16 (m97 pattern)
#define GLDS16(gp, lp) __builtin_amdgcn_global_load_lds( \
    (const __attribute__((address_space(1))) unsigned int*)(gp), \
    (__attribute__((address_space(3))) unsigned int*)(lp), 16, 0, 0)

#define SB0() __builtin_amdgcn_sched_barrier(0)
#define MFMA_BF16(a, b, c) __builtin_amdgcn_mfma_f32_16x16x32_bf16((a), (b), (c), 0, 0, 0)

// ---------------------------------------------------------------------------
// Weight conversion fp32 -> bf16 into one packed ws region (13M elems, 26MB).
// dst element layout: [Wk 1M][Wv 1M][Wr 1M][Wo 1M][Wrec 1M][Wkey 4M][Wval 4M]
// ---------------------------------------------------------------------------
struct WSrc { const float* p[7]; };

__global__ __launch_bounds__(256) void k_convert(WSrc w, unsigned short* __restrict__ dst) {
    size_t e = ((size_t)blockIdx.x * 256 + threadIdx.x) * 4;
    int seg = (int)(e >> 20);
    const float* s; size_t off;
    if (seg < 5)      { s = w.p[seg]; off = e - ((size_t)seg << 20); }
    else if (seg < 9) { s = w.p[5];   off = e - (5ull << 20); }
    else              { s = w.p[6];   off = e - (9ull << 20); }
    float4 v = *(const float4*)(s + off);
    ushort4 o;
    o.x = f2bf(v.x); o.y = f2bf(v.y); o.z = f2bf(v.z); o.w = f2bf(v.w);
    *(ushort4*)(dst + e) = o;
}

// ---------------------------------------------------------------------------
// Fused LayerNorm + time_shift + token-mix. One block per row m = b*T+t.
// ---------------------------------------------------------------------------
template<int THREE>
__global__ __launch_bounds__(256) void k_ln_mix(
    const float* __restrict__ xin, const float* __restrict__ lw, const float* __restrict__ lb,
    const float* __restrict__ tk, const float* __restrict__ tv, const float* __restrict__ tr,
    unsigned short* __restrict__ ok, unsigned short* __restrict__ ov, unsigned short* __restrict__ orr)
{
    __shared__ float sred[4][4];
    const int m = blockIdx.x;
    const int t = m & (T_ - 1);
    const int tid = threadIdx.x;
    const int col0 = tid * 4;

    const float4 xc = *(const float4*)(xin + (size_t)m * C_ + col0);
    float4 xp = make_float4(0.f, 0.f, 0.f, 0.f);
    if (t > 0) xp = *(const float4*)(xin + (size_t)(m - 1) * C_ + col0);

    float s1 = xc.x + xc.y + xc.z + xc.w;
    float s2 = xc.x*xc.x + xc.y*xc.y + xc.z*xc.z + xc.w*xc.w;
    float s3 = xp.x + xp.y + xp.z + xp.w;
    float s4 = xp.x*xp.x + xp.y*xp.y + xp.z*xp.z + xp.w*xp.w;
    #pragma unroll
    for (int off = 32; off > 0; off >>= 1) {
        s1 += __shfl_down(s1, off);
        s2 += __shfl_down(s2, off);
        s3 += __shfl_down(s3, off);
        s4 += __shfl_down(s4, off);
    }
    const int wave = tid >> 6, lane = tid & 63;
    if (lane == 0) { sred[0][wave]=s1; sred[1][wave]=s2; sred[2][wave]=s3; sred[3][wave]=s4; }
    __syncthreads();
    const float S1 = sred[0][0]+sred[0][1]+sred[0][2]+sred[0][3];
    const float S2 = sred[1][0]+sred[1][1]+sred[1][2]+sred[1][3];
    const float S3 = sred[2][0]+sred[2][1]+sred[2][2]+sred[2][3];
    const float S4 = sred[3][0]+sred[3][1]+sred[3][2]+sred[3][3];

    const float inv = 1.0f / (float)C_;
    const float muc = S1 * inv;
    const float rc  = rsqrtf(S2 * inv - muc * muc + 1e-5f);
    const float mup = S3 * inv;
    const float rp  = rsqrtf(S4 * inv - mup * mup + 1e-5f);

    const float xcv[4] = {xc.x, xc.y, xc.z, xc.w};
    const float xpv[4] = {xp.x, xp.y, xp.z, xp.w};
    unsigned short rk[4], rv[4], rr[4];
    #pragma unroll
    for (int i = 0; i < 4; ++i) {
        const int col = col0 + i;
        const float w_ = lw[col], b_ = lb[col];
        const float h  = (xcv[i] - muc) * rc * w_ + b_;
        const float hh = (t > 0) ? (xpv[i] - mup) * rp * w_ + b_ : 0.f;
        const float ak = tk[col];
        rk[i] = f2bf(h * ak + hh * (1.f - ak));
        if (THREE) { const float av = tv[col]; rv[i] = f2bf(h * av + hh * (1.f - av)); }
        const float ar = tr[col];
        rr[i] = f2bf(h * ar + hh * (1.f - ar));
    }
    const size_t o = (size_t)m * C_ + col0;
    ushort4 u;
    u.x = rk[0]; u.y = rk[1]; u.z = rk[2]; u.w = rk[3];
    *(ushort4*)(ok + o) = u;
    if (THREE) {
        u.x = rv[0]; u.y = rv[1]; u.z = rv[2]; u.w = rv[3];
        *(ushort4*)(ov + o) = u;
    }
    u.x = rr[0]; u.y = rr[1]; u.z = rr[2]; u.w = rr[3];
    *(ushort4*)(orr + o) = u;
}

// ---------------------------------------------------------------------------
// WKV pass A: per (b,c,chunk) local state recurrence from zero init.
// ---------------------------------------------------------------------------
__global__ __launch_bounds__(256) void k_wkv_local(
    const unsigned short* __restrict__ kb, const unsigned short* __restrict__ vb,
    const float* __restrict__ tdec, float4* __restrict__ st)
{
    const int g = blockIdx.x * 256 + threadIdx.x;   // 0..131071
    const int c = g & (C_ - 1);
    const int j = (g >> 10) & (NC - 1);
    const int b = g >> 14;
    const float w = -__expf(tdec[c]);
    float aa = 0.f, bb = 0.f, pp = -1e38f;
    const size_t base = ((size_t)(b * T_ + j * LCH)) * C_ + c;
    #pragma unroll 4
    for (int t = 0; t < LCH; ++t) {
        const float kt = bf2f(kb[base + (size_t)t * C_]);
        const float vt = bf2f(vb[base + (size_t)t * C_]);
        const float ww2 = pp + w;
        const float qq2 = fmaxf(ww2, kt);
        const float e1b = __expf(ww2 - qq2);
        const float e2b = __expf(kt - qq2);
        aa = e1b * aa + e2b * vt;
        bb = e1b * bb + e2b;
        pp = qq2;
    }
    st[((size_t)b * NC + j) * C_ + c] = make_float4(aa, bb, pp, 0.f);
}

// ---------------------------------------------------------------------------
// WKV pass C: combine preceding chunk states, replay chunk computing p=sr*y.
// ---------------------------------------------------------------------------
__global__ __launch_bounds__(256) void k_wkv_scan(
    const unsigned short* __restrict__ kb, const unsigned short* __restrict__ vb,
    const unsigned short* __restrict__ sr,
    const float* __restrict__ tdec, const float* __restrict__ tfirst,
    const float4* __restrict__ st, unsigned short* __restrict__ p)
{
    const int g = blockIdx.x * 256 + threadIdx.x;
    const int c = g & (C_ - 1);
    const int j = (g >> 10) & (NC - 1);
    const int b = g >> 14;
    const float w = -__expf(tdec[c]);
    const float u = tfirst[c];

    float aa = 0.f, bb = 0.f, pp = -1e38f;
    for (int i = 0; i < j; ++i) {
        const float4 s = st[((size_t)b * NC + i) * C_ + c];
        const float pdec = pp + w * (float)LCH;
        const float q  = fmaxf(pdec, s.z);
        const float eA = __expf(pdec - q);
        const float eB = __expf(s.z - q);
        aa = eA * aa + eB * s.x;
        bb = eA * bb + eB * s.y;
        pp = q;
    }

    const size_t base = ((size_t)(b * T_ + j * LCH)) * C_ + c;
    #pragma unroll 4
    for (int t = 0; t < LCH; ++t) {
        const size_t idx = base + (size_t)t * C_;
        const float kt = bf2f(kb[idx]);
        const float vt = bf2f(vb[idx]);
        const float ww = u + kt;
        const float qq = fmaxf(pp, ww);
        const float e1 = __expf(pp - qq);
        const float e2 = __expf(ww - qq);
        const float y  = (e1 * aa + e2 * vt) / (e1 * bb + e2);
        p[idx] = f2bf(bf2f(sr[idx]) * y);
        const float ww2 = pp + w;
        const float qq2 = fmaxf(ww2, kt);
        const float e1b = __expf(ww2 - qq2);
        const float e2b = __expf(kt - qq2);
        aa = e1b * aa + e2b * vt;
        bb = e1b * bb + e2b;
        pp = qq2;
    }
}

// ---------------------------------------------------------------------------
// 4-phase/K-tile GEMM core, 2 BARRIERS per K-tile (r6 experiment; r2 had 8).
// BM=BN=256, BK=64, 8 waves (2Mx4N), per-wave C = 128x64 (acc[8][4]).
// LDS = 2 slots x (A 32K + B 32K) = 128 KiB. 1 block/CU.
// Zero-conflict swizzle: 128B rows, 16B block q of row r at q^(r&7);
// pre-swizzled global source + linear LDS dest + XOR'd read (rule #21).
//
// Per K-tile t (slot rs=t&1), stage tile t+1 into ns=rs^1:
//   F0: read B(8)+A01(4) | stage A(t+1){0,2} | lgkm(0) | MFMA rows 0,1
//   F1: read A23          | stage B(t+1) all  | lgkm(0) | MFMA rows 2,3
//       -> vmcnt(6) -> BARRIER   [proves A(t) h1 to all waves]
//   F2: read A45          | stage A(t+1){1,3} | lgkm(0) | MFMA rows 4,5
//   F3: read A67          |                   | lgkm(0) | MFMA rows 6,7
//       -> vmcnt(2) -> BARRIER   [proves A(t+1) h0 + B(t+1)]
//
// Hazard proofs (each = own-wave wait -> barrier -> cross-wave use):
//  RAW B(t),A(t)h0: vmcnt(2)@F3(t-1) proves them; endF3(t-1) barrier < F0(t).
//  RAW A(t)h1:      vmcnt(6)@F1(t) proves it;     endF1(t) barrier < F2(t).
//  WAR stA{0,2}/stB into ns @F0/F1(t): prior reads of those units ended by
//    F1(t-1) lgkm(0); endF1(t-1) barrier < F0(t).
//  WAR stA{1,3} into ns @F2(t): prior reads ended by F3(t-1) lgkm(0);
//    endF3(t-1) barrier < F2(t).
// Counted vmcnt never drains to 0 in the loop (T4). SB0 after each wait
// (rule #18: keep MFMA from hoisting past inline-asm lgkmcnt).
// ---------------------------------------------------------------------------
static __device__ __forceinline__ void gemm_core256(
    const unsigned short* __restrict__ A, int lda,
    const unsigned short* __restrict__ Bw, int ldb,
    int K, int m0, int n0,
    unsigned short* As, unsigned short* Bs, f32x4 acc[8][4])
{
    const int tid  = threadIdx.x;
    const int l    = tid & 63;
    const int l16  = l & 15, quad = l >> 4;
    const int w    = tid >> 6;
    const int wm   = w >> 2, wn = w & 3;        // 2 x 4 wave grid

    // ---- staging source addressing (pre-swizzled global, linear LDS dest)
    const int sr_ = tid >> 3;                    // 0..63
    const int sb_ = (tid & 7) ^ (sr_ & 7);       // swizzled 16B source block
    const unsigned short* gA = A  + (size_t)(m0 + sr_) * lda + sb_ * 8;
    const unsigned short* gB = Bw + (size_t)(n0 + sr_) * ldb + sb_ * 8;

    auto stA = [&](int tt, int ss, int u) {
        GLDS16(gA + (size_t)u * 64 * lda + tt * 64, As + ss * 16384 + u * 4096 + w * 512);
    };
    auto stB = [&](int tt, int ss, int u) {
        GLDS16(gB + (size_t)u * 64 * ldb + tt * 64, Bs + ss * 16384 + u * 4096 + w * 512);
    };

    // ---- fragment read addressing: row = band + frag*16 + l16 (row&7=l16&7);
    // logical block = s*4+quad (K-step s), physical = logical ^ (l16&7).
    const int swz = l16 & 7;
    const unsigned short* aR = As + (wm * 128 + l16) * 64;
    const unsigned short* bR = Bs + (wn * 64  + l16) * 64;
    const int o0 = ((0 + quad) ^ swz) * 8;       // K-step 0
    const int o1 = ((4 + quad) ^ swz) * 8;       // K-step 1

    // ---- prologue: stage tile 0 fully, one-time drain
    stA(0, 0, 0); stA(0, 0, 2);
    stB(0, 0, 0); stB(0, 0, 1); stB(0, 0, 2); stB(0, 0, 3);
    stA(0, 0, 1); stA(0, 0, 3);
    asm volatile("s_waitcnt vmcnt(0)" ::: "memory");
    SB0();
    __builtin_amdgcn_s_barrier();
    SB0();

    const int NT = K >> 6;
    for (int t = 0; t < NT; ++t) {
        const int rs = t & 1, ns = rs ^ 1;
        const unsigned short* ab = aR + rs * 16384;
        const unsigned short* bb = bR + rs * 16384;
        const bool pf = (t + 1 < NT);
        bf16x8 b0[4], b1[4];

        // ===== F0: B frags + A01; stage A(t+1){0,2}; no barrier =====
        {
            bf16x8 a0[2], a1[2];
            #pragma unroll
            for (int j = 0; j < 4; ++j) {
                b0[j] = *(const bf16x8*)(bb + j * 1024 + o0);
                b1[j] = *(const bf16x8*)(bb + j * 1024 + o1);
            }
            #pragma unroll
            for (int i = 0; i < 2; ++i) {
                a0[i] = *(const bf16x8*)(ab + i * 1024 + o0);
                a1[i] = *(const bf16x8*)(ab + i * 1024 + o1);
            }
            if (pf) { stA(t + 1, ns, 0); stA(t + 1, ns, 2); }
            asm volatile("s_waitcnt lgkmcnt(0)" ::: "memory");
            SB0();
            __builtin_amdgcn_s_setprio(1);
            #pragma unroll
            for (int i = 0; i < 2; ++i)
                #pragma unroll
                for (int j = 0; j < 4; ++j) {
                    acc[i][j] = MFMA_BF16(a0[i], b0[j], acc[i][j]);
                    acc[i][j] = MFMA_BF16(a1[i], b1[j], acc[i][j]);
                }
            __builtin_amdgcn_s_setprio(0);
            SB0();
        }

        // ===== F1: A23; stage B(t+1); vmcnt(6); BARRIER =====
        {
            bf16x8 a0[2], a1[2];
            #pragma unroll
            for (int i = 0; i < 2; ++i) {
                a0[i] = *(const bf16x8*)(ab + (2 + i) * 1024 + o0);
                a1[i] = *(const bf16x8*)(ab + (2 + i) * 1024 + o1);
            }
            if (pf) { stB(t + 1, ns, 0); stB(t + 1, ns, 1); stB(t + 1, ns, 2); stB(t + 1, ns, 3); }
            asm volatile("s_waitcnt lgkmcnt(0)" ::: "memory");
            SB0();
            __builtin_amdgcn_s_setprio(1);
            #pragma unroll
            for (int i = 0; i < 2; ++i)
                #pragma unroll
                for (int j = 0; j < 4; ++j) {
                    acc[2 + i][j] = MFMA_BF16(a0[i], b0[j], acc[2 + i][j]);
                    acc[2 + i][j] = MFMA_BF16(a1[i], b1[j], acc[2 + i][j]);
                }
            __builtin_amdgcn_s_setprio(0);
            asm volatile("s_waitcnt vmcnt(6)" ::: "memory");
            SB0();
            __builtin_amdgcn_s_barrier();
            SB0();
        }

        // ===== F2: A45; stage A(t+1){1,3}; no barrier =====
        {
            bf16x8 a0[2], a1[2];
            #pragma unroll
            for (int i = 0; i < 2; ++i) {
                a0[i] = *(const bf16x8*)(ab + (4 + i) * 1024 + o0);
                a1[i] = *(const bf16x8*)(ab + (4 + i) * 1024 + o1);
            }
            if (pf) { stA(t + 1, ns, 1); stA(t + 1, ns, 3); }
            asm volatile("s_waitcnt lgkmcnt(0)" ::: "memory");
            SB0();
            __builtin_amdgcn_s_setprio(1);
            #pragma unroll
            for (int i = 0; i < 2; ++i)
                #pragma unroll
                for (int j = 0; j < 4; ++j) {
                    acc[4 + i][j] = MFMA_BF16(a0[i], b0[j], acc[4 + i][j]);
                    acc[4 + i][j] = MFMA_BF16(a1[i], b1[j], acc[4 + i][j]);
                }
            __builtin_amdgcn_s_setprio(0);
            SB0();
        }

        // ===== F3: A67; vmcnt(2); BARRIER =====
        {
            bf16x8 a0[2], a1[2];
            #pragma unroll
            for (int i = 0; i < 2; ++i) {
                a0[i] = *(const bf16x8*)(ab + (6 + i) * 1024 + o0);
                a1[i] = *(const bf16x8*)(ab + (6 + i) * 1024 + o1);
            }
            asm volatile("s_waitcnt lgkmcnt(0)" ::: "memory");
            SB0();
            __builtin_amdgcn_s_setprio(1);
            #pragma unroll
            for (int i = 0; i < 2; ++i)
                #pragma unroll
                for (int j = 0; j < 4; ++j) {
                    acc[6 + i][j] = MFMA_BF16(a0[i], b0[j], acc[6 + i][j]);
                    acc[6 + i][j] = MFMA_BF16(a1[i], b1[j], acc[6 + i][j]);
                }
            __builtin_amdgcn_s_setprio(0);
            asm volatile("s_waitcnt vmcnt(2)" ::: "memory");
            SB0();
            __builtin_amdgcn_s_barrier();
            SB0();
        }
    }
}

// Generic GEMM. EPI: 1 = sigmoid->bf16; 2 = resid + acc -> fp32;
//                3 = relu(acc)^2 -> bf16; 4 = outF += bf16(mul)*acc
template<int EPI>
__global__ __launch_bounds__(512, 1) void k_gemm(
    const unsigned short* __restrict__ A, int lda,
    const unsigned short* __restrict__ Bw, int ldb,
    int K, int N,
    float* __restrict__ outF, unsigned short* __restrict__ outH,
    const float* __restrict__ resid, const unsigned short* __restrict__ mul)
{
    __shared__ unsigned short As[2 * 16384];   // 64 KiB
    __shared__ unsigned short Bs[2 * 16384];   // 64 KiB
    f32x4 acc[8][4];
    const f32x4 zero = {0.f, 0.f, 0.f, 0.f};
    #pragma unroll
    for (int i = 0; i < 8; ++i)
        #pragma unroll
        for (int j = 0; j < 4; ++j) acc[i][j] = zero;

    const int m0 = blockIdx.x * 256, n0 = blockIdx.y * 256;
    gemm_core256(A, lda, Bw, ldb, K, m0, n0, As, Bs, acc);

    const int lane = threadIdx.x & 63, wave = threadIdx.x >> 6;
    const int quad = lane >> 4, l16 = lane & 15;
    const int wm = (wave >> 2) * 128, wn = (wave & 3) * 64;
    #pragma unroll
    for (int i = 0; i < 8; ++i) {
        const int rowb = m0 + wm + i * 16 + quad * 4;
        #pragma unroll
        for (int j = 0; j < 4; ++j) {
            const int col = n0 + wn + j * 16 + l16;
            #pragma unroll
            for (int r = 0; r < 4; ++r) {
                const size_t idx = (size_t)(rowb + r) * N + col;
                const float v = acc[i][j][r];
                if (EPI == 1)      outH[idx] = f2bf(1.f / (1.f + __expf(-v)));
                else if (EPI == 2) outF[idx] = resid[idx] + v;
                else if (EPI == 3) { const float z = v > 0.f ? v : 0.f; outH[idx] = f2bf(z * z); }
                else               outF[idx] = outF[idx] + bf2f(mul[idx]) * v;
            }
        }
    }
}

// Fused k/v/r projection: one dispatch vs packed [Wk;Wv;Wr] (N=3072).
// n-segment (n0>>10, uniform per block) selects BOTH the A input (xk/xv/xr)
// and the output (k->ok, v->ov, sigmoid(r)->orr). 256-tiles divide 1024.
__global__ __launch_bounds__(512, 1) void k_gemm_kvr(
    const unsigned short* __restrict__ xk, const unsigned short* __restrict__ xv,
    const unsigned short* __restrict__ xr,
    const unsigned short* __restrict__ W3,
    unsigned short* __restrict__ ok, unsigned short* __restrict__ ov,
    unsigned short* __restrict__ orr)
{
    __shared__ unsigned short As[2 * 16384];
    __shared__ unsigned short Bs[2 * 16384];
    f32x4 acc[8][4];
    const f32x4 zero = {0.f, 0.f, 0.f, 0.f};
    #pragma unroll
    for (int i = 0; i < 8; ++i)
        #pragma unroll
        for (int j = 0; j < 4; ++j) acc[i][j] = zero;

    const int m0 = blockIdx.x * 256, n0 = blockIdx.y * 256;
    const int seg = n0 >> 10;                       // 0=k 1=v 2=r
    const unsigned short* A = (seg == 0) ? xk : (seg == 1) ? xv : xr;
    unsigned short* outH    = (seg == 0) ? ok : (seg == 1) ? ov : orr;

    gemm_core256(A, C_, W3, C_, C_, m0, n0, As, Bs, acc);

    const int nl0 = n0 & (C_ - 1);
    const int lane = threadIdx.x & 63, wave = threadIdx.x >> 6;
    const int quad = lane >> 4, l16 = lane & 15;
    const int wm = (wave >> 2) * 128, wn = (wave & 3) * 64;
    #pragma unroll
    for (int i = 0; i < 8; ++i) {
        const int rowb = m0 + wm + i * 16 + quad * 4;
        #pragma unroll
        for (int j = 0; j < 4; ++j) {
            const int col = nl0 + wn + j * 16 + l16;
            #pragma unroll
            for (int r = 0; r < 4; ++r) {
                const size_t idx = (size_t)(rowb + r) * C_ + col;
                float v = acc[i][j][r];
                if (seg == 2) v = 1.f / (1.f + __expf(-v));
                outH[idx] = f2bf(v);
            }
        }
    }
}

// ---------------------------------------------------------------------------
// Workspace layout (peak 154 MB):
//   [0,32)MB    xk   -> WKV states (2MB) -> xk2
//   [32,64)     xv   -> p (Wo input)     -> s2
//   [64,96)     xr   -> kk[0:32MB)
//   [96,128)    sr   -> xr2              -> kk[32:64MB)
//   [128,154)   bf16 weights ([Wk;Wv;Wr] contiguous for fused GEMM)
// k,v (bf16, 32MB each) live in d_out until step 5 overwrites it.
// FFN runs in 2 chunks of F=2048 through the 64MB kk buffer at [64,128).
// ---------------------------------------------------------------------------
extern "C" void kernel_launch(void* const* d_in, const int* in_sizes, int n_in,
                              void* d_out, int out_size, void* d_ws, size_t ws_size,
                              hipStream_t stream)
{
    const float* x      = (const float*)d_in[0];
    const float* ln1w   = (const float*)d_in[1];
    const float* ln1b   = (const float*)d_in[2];
    const float* ln2w   = (const float*)d_in[3];
    const float* ln2b   = (const float*)d_in[4];
    const float* atk    = (const float*)d_in[5];
    const float* atv    = (const float*)d_in[6];
    const float* atr    = (const float*)d_in[7];
    const float* tdec   = (const float*)d_in[8];
    const float* tfirst = (const float*)d_in[9];
    const float* Wk     = (const float*)d_in[10];
    const float* Wv     = (const float*)d_in[11];
    const float* Wr     = (const float*)d_in[12];
    const float* Wo     = (const float*)d_in[13];
    const float* ftk    = (const float*)d_in[14];
    const float* ftr    = (const float*)d_in[15];
    const float* Wkey   = (const float*)d_in[16];
    const float* Wrec   = (const float*)d_in[17];
    const float* Wval   = (const float*)d_in[18];
    float* out = (float*)d_out;

    char* ws = (char*)d_ws;
    const size_t MB = 1ull << 20;
    unsigned short* xk  = (unsigned short*)(ws + 0 * MB);
    unsigned short* xv  = (unsigned short*)(ws + 32 * MB);
    unsigned short* xr  = (unsigned short*)(ws + 64 * MB);
    unsigned short* sr  = (unsigned short*)(ws + 96 * MB);
    unsigned short* wb  = (unsigned short*)(ws + 128 * MB);
    float4* states      = (float4*)(ws + 0 * MB);   // 2MB, xk dead after kvr GEMM
    unsigned short* p   = xv;   // p overwrites xv (dead after kvr GEMM)
    unsigned short* xk2 = xk;                             // [0,32)
    unsigned short* xr2 = (unsigned short*)(ws + 96 * MB); // [96,128), sr dead after wkv_scan
    unsigned short* s2  = (unsigned short*)(ws + 32 * MB); // [32,64), p dead after Wo GEMM
    unsigned short* kk  = (unsigned short*)(ws + 64 * MB); // [64,128), 64MB: 16384 x 2048 bf16
    unsigned short* kb  = (unsigned short*)d_out;             // 32MB
    unsigned short* vb  = (unsigned short*)d_out + (32*MB/2); // 32MB

    unsigned short* W3_b   = wb;                   // [Wk;Wv;Wr] 3072x1024
    unsigned short* Wo_b   = wb + 3 * (1u << 20);
    unsigned short* Wrec_b = wb + 4 * (1u << 20);
    unsigned short* Wkey_b = wb + 5 * (1u << 20);
    unsigned short* Wval_b = wb + 9 * (1u << 20);

    // 1) weights -> bf16
    WSrc wsrc; wsrc.p[0]=Wk; wsrc.p[1]=Wv; wsrc.p[2]=Wr; wsrc.p[3]=Wo;
    wsrc.p[4]=Wrec; wsrc.p[5]=Wkey; wsrc.p[6]=Wval;
    k_convert<<<dim3(13312), dim3(256), 0, stream>>>(wsrc, wb);

    // 2) LN1 + time-shift mix -> xk, xv, xr (bf16)
    k_ln_mix<1><<<dim3(M_), dim3(256), 0, stream>>>(x, ln1w, ln1b, atk, atv, atr, xk, xv, xr);

    // 3) fused k/v/r projections (N=3072): k->kb, v->vb, sigmoid(r)->sr
    k_gemm_kvr<<<dim3(64, 12), dim3(512), 0, stream>>>(xk, xv, xr, W3_b, kb, vb, sr);

    // 4) WKV: chunk-parallel scan
    k_wkv_local<<<dim3(512), dim3(256), 0, stream>>>(kb, vb, tdec, states);
    k_wkv_scan<<<dim3(512), dim3(256), 0, stream>>>(kb, vb, sr, tdec, tfirst, states, p);

    // 5) x1 = x + p @ Wo^T -> d_out (fp32)
    k_gemm<2><<<dim3(64, 4), dim3(512), 0, stream>>>(p, 1024, Wo_b, 1024, 1024, 1024, out, (unsigned short*)nullptr, x, (const unsigned short*)nullptr);

    // 6) LN2 + time-shift mix -> xk2 [0,32), xr2 [96,128) (bf16)
    k_ln_mix<0><<<dim3(M_), dim3(256), 0, stream>>>(out, ln2w, ln2b, ftk, (const float*)nullptr, ftr, xk2, (unsigned short*)nullptr, xr2);

    // 7) s2 = sigmoid(xr2 @ Wrec^T) (bf16) -> [32,64); frees xr2 region
    k_gemm<1><<<dim3(64, 4), dim3(512), 0, stream>>>(xr2, 1024, Wrec_b, 1024, 1024, 1024, (float*)nullptr, s2, (const float*)nullptr, (const unsigned short*)nullptr);

    // 8) FFN in 2 chunks of F=2048: kk = relu(xk2@Wkey_c^T)^2 (N=2048),
    //    then out += s2 * (kk @ Wval_c^T) (K=2048)
    for (int c = 0; c < 2; ++c) {
        const unsigned short* WkeyC = Wkey_b + (size_t)c * 2048 * 1024;
        const unsigned short* WvalC = Wval_b + (size_t)c * 2048;
        k_gemm<3><<<dim3(64, 8), dim3(512), 0, stream>>>(xk2, 1024, WkeyC, 1024, 1024, 2048, (float*)nullptr, kk, (const float*)nullptr, (const unsigned short*)nullptr);
        k_gemm<4><<<dim3(64, 4), dim3(512), 0, stream>>>(kk, 2048, WvalC, 4096, 2048, 1024, out, (unsigned short*)nullptr, (const float*)nullptr, s2);
    }
}

// Round 7
// 818.394 us; speedup vs baseline: 1.1762x; 1.0399x over previous
//
#include <hip/hip_runtime.h>
#include <stdint.h>

// RWKV-4 block: B=8, T=2048, C=1024, DIM_FFN=4096, fp32 in/out, bf16 MFMA internally.
#define B_ 8
#define T_ 2048
#define C_ 1024
#define F_ 4096
#define M_ (B_*T_)   // 16384 rows
#define NC 16        // WKV chunks per sequence
#define LCH (T_/NC)  // 128 steps per chunk

typedef __attribute__((ext_vector_type(8))) short bf16x8;   // MFMA A/B frag (4 VGPRs)
typedef __attribute__((ext_vector_type(4))) float f32x4;    // MFMA C/D frag

static __device__ __forceinline__ unsigned short f2bf(float f) {
    union { float f; unsigned u; } v; v.f = f;
    unsigned r = v.u + 0x7fffu + ((v.u >> 16) & 1u);  // RNE
    return (unsigned short)(r >> 16);
}
static __device__ __forceinline__ float bf2f(unsigned short h) {
    union { unsigned u; float f; } v; v.u = ((unsigned)h) << 16;
    return v.f;
}

// async global->LDS, 16B/lane, wave-uniform LDS base + lane*16 (m97 pattern)
#define GLDS16(gp, lp) __builtin_amdgcn_global_load_lds( \
    (const __attribute__((address_space(1))) unsigned int*)(gp), \
    (__attribute__((address_space(3))) unsigned int*)(lp), 16, 0, 0)

#define SB0() __builtin_amdgcn_sched_barrier(0)
#define MFMA_BF16(a, b, c) __builtin_amdgcn_mfma_f32_16x16x32_bf16((a), (b), (c), 0, 0, 0)

// ---------------------------------------------------------------------------
// Weight conversion fp32 -> bf16 into one packed ws region (13M elems, 26MB).
// dst element layout: [Wk 1M][Wv 1M][Wr 1M][Wo 1M][Wrec 1M][Wkey 4M][Wval 4M]
// ---------------------------------------------------------------------------
struct WSrc { const float* p[7]; };

__global__ __launch_bounds__(256) void k_convert(WSrc w, unsigned short* __restrict__ dst) {
    size_t e = ((size_t)blockIdx.x * 256 + threadIdx.x) * 4;
    int seg = (int)(e >> 20);
    const float* s; size_t off;
    if (seg < 5)      { s = w.p[seg]; off = e - ((size_t)seg << 20); }
    else if (seg < 9) { s = w.p[5];   off = e - (5ull << 20); }
    else              { s = w.p[6];   off = e - (9ull << 20); }
    float4 v = *(const float4*)(s + off);
    ushort4 o;
    o.x = f2bf(v.x); o.y = f2bf(v.y); o.z = f2bf(v.z); o.w = f2bf(v.w);
    *(ushort4*)(dst + e) = o;
}

// ---------------------------------------------------------------------------
// Fused LayerNorm + time_shift + token-mix, 8 ROWS PER BLOCK (r7):
// load row r-1 once, normalize once, reuse its h as next row's hh.
// Halves x reads (2x -> 1.125x) and halves the reductions vs 1-row blocks;
// 2048 blocks x 4 waves = fully resident (32 waves/CU).
// ---------------------------------------------------------------------------
template<int THREE>
__global__ __launch_bounds__(256) void k_ln_mix(
    const float* __restrict__ xin, const float* __restrict__ lw, const float* __restrict__ lb,
    const float* __restrict__ tk, const float* __restrict__ tv, const float* __restrict__ tr,
    unsigned short* __restrict__ ok, unsigned short* __restrict__ ov, unsigned short* __restrict__ orr)
{
    __shared__ float sred[2][2][4];   // [parity][sum/sumsq][wave]
    const int r0  = blockIdx.x * 8;
    const int t0  = r0 & (T_ - 1);
    const int tid = threadIdx.x;
    const int wave = tid >> 6, lane = tid & 63;
    const int col0 = tid * 4;
    const float inv = 1.0f / (float)C_;

    // per-column constants (uniform over the 8 rows)
    float wv_[4], bv_[4], akv[4], avv[4], arv[4];
    #pragma unroll
    for (int i = 0; i < 4; ++i) {
        wv_[i] = lw[col0 + i];
        bv_[i] = lb[col0 + i];
        akv[i] = tk[col0 + i];
        if (THREE) avv[i] = tv[col0 + i];
        arv[i] = tr[col0 + i];
    }

    int par = 0;
    // block-wide 2-sum reduction (sum, sumsq); 1 barrier per call, parity-dbuf
    auto reduce2 = [&](float a, float b, float& A, float& B) {
        #pragma unroll
        for (int off = 32; off > 0; off >>= 1) {
            a += __shfl_down(a, off);
            b += __shfl_down(b, off);
        }
        if (lane == 0) { sred[par][0][wave] = a; sred[par][1][wave] = b; }
        __syncthreads();
        A = sred[par][0][0] + sred[par][0][1] + sred[par][0][2] + sred[par][0][3];
        B = sred[par][1][0] + sred[par][1][1] + sred[par][1][2] + sred[par][1][3];
        par ^= 1;
    };

    float hp[4] = {0.f, 0.f, 0.f, 0.f};   // previous row's normalized h
    const bool havePrev = (t0 > 0);
    if (havePrev) {
        const float4 xp = *(const float4*)(xin + (size_t)(r0 - 1) * C_ + col0);
        float S1, S2;
        reduce2(xp.x + xp.y + xp.z + xp.w,
                xp.x*xp.x + xp.y*xp.y + xp.z*xp.z + xp.w*xp.w, S1, S2);
        const float mu = S1 * inv;
        const float rs = rsqrtf(S2 * inv - mu * mu + 1e-5f);
        const float xv[4] = {xp.x, xp.y, xp.z, xp.w};
        #pragma unroll
        for (int i = 0; i < 4; ++i) hp[i] = (xv[i] - mu) * rs * wv_[i] + bv_[i];
    }

    for (int rrow = 0; rrow < 8; ++rrow) {
        const int m = r0 + rrow;
        const float4 xc = *(const float4*)(xin + (size_t)m * C_ + col0);
        float S1, S2;
        reduce2(xc.x + xc.y + xc.z + xc.w,
                xc.x*xc.x + xc.y*xc.y + xc.z*xc.z + xc.w*xc.w, S1, S2);
        const float mu = S1 * inv;
        const float rs = rsqrtf(S2 * inv - mu * mu + 1e-5f);
        const bool z = (rrow == 0) && !havePrev;   // t == 0: hh = 0

        const float xv[4] = {xc.x, xc.y, xc.z, xc.w};
        unsigned short rk[4], rv[4], rr[4];
        #pragma unroll
        for (int i = 0; i < 4; ++i) {
            const float h  = (xv[i] - mu) * rs * wv_[i] + bv_[i];
            const float hh = z ? 0.f : hp[i];
            rk[i] = f2bf(h * akv[i] + hh * (1.f - akv[i]));
            if (THREE) rv[i] = f2bf(h * avv[i] + hh * (1.f - avv[i]));
            rr[i] = f2bf(h * arv[i] + hh * (1.f - arv[i]));
            hp[i] = h;
        }
        const size_t o = (size_t)m * C_ + col0;
        ushort4 u;
        u.x = rk[0]; u.y = rk[1]; u.z = rk[2]; u.w = rk[3];
        *(ushort4*)(ok + o) = u;
        if (THREE) {
            u.x = rv[0]; u.y = rv[1]; u.z = rv[2]; u.w = rv[3];
            *(ushort4*)(ov + o) = u;
        }
        u.x = rr[0]; u.y = rr[1]; u.z = rr[2]; u.w = rr[3];
        *(ushort4*)(orr + o) = u;
    }
}

// ---------------------------------------------------------------------------
// WKV pass A: per (b,c,chunk) local state recurrence from zero init.
// ---------------------------------------------------------------------------
__global__ __launch_bounds__(256) void k_wkv_local(
    const unsigned short* __restrict__ kb, const unsigned short* __restrict__ vb,
    const float* __restrict__ tdec, float4* __restrict__ st)
{
    const int g = blockIdx.x * 256 + threadIdx.x;   // 0..131071
    const int c = g & (C_ - 1);
    const int j = (g >> 10) & (NC - 1);
    const int b = g >> 14;
    const float w = -__expf(tdec[c]);
    float aa = 0.f, bb = 0.f, pp = -1e38f;
    const size_t base = ((size_t)(b * T_ + j * LCH)) * C_ + c;
    #pragma unroll 4
    for (int t = 0; t < LCH; ++t) {
        const float kt = bf2f(kb[base + (size_t)t * C_]);
        const float vt = bf2f(vb[base + (size_t)t * C_]);
        const float ww2 = pp + w;
        const float qq2 = fmaxf(ww2, kt);
        const float e1b = __expf(ww2 - qq2);
        const float e2b = __expf(kt - qq2);
        aa = e1b * aa + e2b * vt;
        bb = e1b * bb + e2b;
        pp = qq2;
    }
    st[((size_t)b * NC + j) * C_ + c] = make_float4(aa, bb, pp, 0.f);
}

// ---------------------------------------------------------------------------
// WKV pass C: combine preceding chunk states, replay chunk computing p=sr*y.
// ---------------------------------------------------------------------------
__global__ __launch_bounds__(256) void k_wkv_scan(
    const unsigned short* __restrict__ kb, const unsigned short* __restrict__ vb,
    const unsigned short* __restrict__ sr,
    const float* __restrict__ tdec, const float* __restrict__ tfirst,
    const float4* __restrict__ st, unsigned short* __restrict__ p)
{
    const int g = blockIdx.x * 256 + threadIdx.x;
    const int c = g & (C_ - 1);
    const int j = (g >> 10) & (NC - 1);
    const int b = g >> 14;
    const float w = -__expf(tdec[c]);
    const float u = tfirst[c];

    float aa = 0.f, bb = 0.f, pp = -1e38f;
    for (int i = 0; i < j; ++i) {
        const float4 s = st[((size_t)b * NC + i) * C_ + c];
        const float pdec = pp + w * (float)LCH;
        const float q  = fmaxf(pdec, s.z);
        const float eA = __expf(pdec - q);
        const float eB = __expf(s.z - q);
        aa = eA * aa + eB * s.x;
        bb = eA * bb + eB * s.y;
        pp = q;
    }

    const size_t base = ((size_t)(b * T_ + j * LCH)) * C_ + c;
    #pragma unroll 4
    for (int t = 0; t < LCH; ++t) {
        const size_t idx = base + (size_t)t * C_;
        const float kt = bf2f(kb[idx]);
        const float vt = bf2f(vb[idx]);
        const float ww = u + kt;
        const float qq = fmaxf(pp, ww);
        const float e1 = __expf(pp - qq);
        const float e2 = __expf(ww - qq);
        const float y  = (e1 * aa + e2 * vt) / (e1 * bb + e2);
        p[idx] = f2bf(bf2f(sr[idx]) * y);
        const float ww2 = pp + w;
        const float qq2 = fmaxf(ww2, kt);
        const float e1b = __expf(ww2 - qq2);
        const float e2b = __expf(kt - qq2);
        aa = e1b * aa + e2b * vt;
        bb = e1b * bb + e2b;
        pp = qq2;
    }
}

// ---------------------------------------------------------------------------
// 4-phase/K-tile GEMM core, 2 BARRIERS per K-tile (r6, best measured: 817 TF).
// BM=BN=256, BK=64, 8 waves (2Mx4N), per-wave C = 128x64 (acc[8][4]).
// LDS = 2 slots x (A 32K + B 32K) = 128 KiB. 1 block/CU.
// Zero-conflict swizzle: 128B rows, 16B block q of row r at q^(r&7);
// pre-swizzled global source + linear LDS dest + XOR'd read (rule #21).
//
// Per K-tile t (slot rs=t&1), stage tile t+1 into ns=rs^1:
//   F0: read B(8)+A01(4) | stage A(t+1){0,2} | lgkm(0) | MFMA rows 0,1
//   F1: read A23          | stage B(t+1) all  | lgkm(0) | MFMA rows 2,3
//       -> vmcnt(6) -> BARRIER   [proves A(t) h1 to all waves]
//   F2: read A45          | stage A(t+1){1,3} | lgkm(0) | MFMA rows 4,5
//   F3: read A67          |                   | lgkm(0) | MFMA rows 6,7
//       -> vmcnt(2) -> BARRIER   [proves A(t+1) h0 + B(t+1)]
//
// Hazard proofs (each = own-wave wait -> barrier -> cross-wave use):
//  RAW B(t),A(t)h0: vmcnt(2)@F3(t-1) proves them; endF3(t-1) barrier < F0(t).
//  RAW A(t)h1:      vmcnt(6)@F1(t) proves it;     endF1(t) barrier < F2(t).
//  WAR stA{0,2}/stB into ns @F0/F1(t): prior reads of those units ended by
//    F1(t-1) lgkm(0); endF1(t-1) barrier < F0(t).
//  WAR stA{1,3} into ns @F2(t): prior reads ended by F3(t-1) lgkm(0);
//    endF3(t-1) barrier < F2(t).
// Counted vmcnt never drains to 0 in the loop (T4). SB0 after each wait
// (rule #18: keep MFMA from hoisting past inline-asm lgkmcnt).
// ---------------------------------------------------------------------------
static __device__ __forceinline__ void gemm_core256(
    const unsigned short* __restrict__ A, int lda,
    const unsigned short* __restrict__ Bw, int ldb,
    int K, int m0, int n0,
    unsigned short* As, unsigned short* Bs, f32x4 acc[8][4])
{
    const int tid  = threadIdx.x;
    const int l    = tid & 63;
    const int l16  = l & 15, quad = l >> 4;
    const int w    = tid >> 6;
    const int wm   = w >> 2, wn = w & 3;        // 2 x 4 wave grid

    // ---- staging source addressing (pre-swizzled global, linear LDS dest)
    const int sr_ = tid >> 3;                    // 0..63
    const int sb_ = (tid & 7) ^ (sr_ & 7);       // swizzled 16B source block
    const unsigned short* gA = A  + (size_t)(m0 + sr_) * lda + sb_ * 8;
    const unsigned short* gB = Bw + (size_t)(n0 + sr_) * ldb + sb_ * 8;

    auto stA = [&](int tt, int ss, int u) {
        GLDS16(gA + (size_t)u * 64 * lda + tt * 64, As + ss * 16384 + u * 4096 + w * 512);
    };
    auto stB = [&](int tt, int ss, int u) {
        GLDS16(gB + (size_t)u * 64 * ldb + tt * 64, Bs + ss * 16384 + u * 4096 + w * 512);
    };

    // ---- fragment read addressing: row = band + frag*16 + l16 (row&7=l16&7);
    // logical block = s*4+quad (K-step s), physical = logical ^ (l16&7).
    const int swz = l16 & 7;
    const unsigned short* aR = As + (wm * 128 + l16) * 64;
    const unsigned short* bR = Bs + (wn * 64  + l16) * 64;
    const int o0 = ((0 + quad) ^ swz) * 8;       // K-step 0
    const int o1 = ((4 + quad) ^ swz) * 8;       // K-step 1

    // ---- prologue: stage tile 0 fully, one-time drain
    stA(0, 0, 0); stA(0, 0, 2);
    stB(0, 0, 0); stB(0, 0, 1); stB(0, 0, 2); stB(0, 0, 3);
    stA(0, 0, 1); stA(0, 0, 3);
    asm volatile("s_waitcnt vmcnt(0)" ::: "memory");
    SB0();
    __builtin_amdgcn_s_barrier();
    SB0();

    const int NT = K >> 6;
    for (int t = 0; t < NT; ++t) {
        const int rs = t & 1, ns = rs ^ 1;
        const unsigned short* ab = aR + rs * 16384;
        const unsigned short* bb = bR + rs * 16384;
        const bool pf = (t + 1 < NT);
        bf16x8 b0[4], b1[4];

        // ===== F0: B frags + A01; stage A(t+1){0,2}; no barrier =====
        {
            bf16x8 a0[2], a1[2];
            #pragma unroll
            for (int j = 0; j < 4; ++j) {
                b0[j] = *(const bf16x8*)(bb + j * 1024 + o0);
                b1[j] = *(const bf16x8*)(bb + j * 1024 + o1);
            }
            #pragma unroll
            for (int i = 0; i < 2; ++i) {
                a0[i] = *(const bf16x8*)(ab + i * 1024 + o0);
                a1[i] = *(const bf16x8*)(ab + i * 1024 + o1);
            }
            if (pf) { stA(t + 1, ns, 0); stA(t + 1, ns, 2); }
            asm volatile("s_waitcnt lgkmcnt(0)" ::: "memory");
            SB0();
            __builtin_amdgcn_s_setprio(1);
            #pragma unroll
            for (int i = 0; i < 2; ++i)
                #pragma unroll
                for (int j = 0; j < 4; ++j) {
                    acc[i][j] = MFMA_BF16(a0[i], b0[j], acc[i][j]);
                    acc[i][j] = MFMA_BF16(a1[i], b1[j], acc[i][j]);
                }
            __builtin_amdgcn_s_setprio(0);
            SB0();
        }

        // ===== F1: A23; stage B(t+1); vmcnt(6); BARRIER =====
        {
            bf16x8 a0[2], a1[2];
            #pragma unroll
            for (int i = 0; i < 2; ++i) {
                a0[i] = *(const bf16x8*)(ab + (2 + i) * 1024 + o0);
                a1[i] = *(const bf16x8*)(ab + (2 + i) * 1024 + o1);
            }
            if (pf) { stB(t + 1, ns, 0); stB(t + 1, ns, 1); stB(t + 1, ns, 2); stB(t + 1, ns, 3); }
            asm volatile("s_waitcnt lgkmcnt(0)" ::: "memory");
            SB0();
            __builtin_amdgcn_s_setprio(1);
            #pragma unroll
            for (int i = 0; i < 2; ++i)
                #pragma unroll
                for (int j = 0; j < 4; ++j) {
                    acc[2 + i][j] = MFMA_BF16(a0[i], b0[j], acc[2 + i][j]);
                    acc[2 + i][j] = MFMA_BF16(a1[i], b1[j], acc[2 + i][j]);
                }
            __builtin_amdgcn_s_setprio(0);
            asm volatile("s_waitcnt vmcnt(6)" ::: "memory");
            SB0();
            __builtin_amdgcn_s_barrier();
            SB0();
        }

        // ===== F2: A45; stage A(t+1){1,3}; no barrier =====
        {
            bf16x8 a0[2], a1[2];
            #pragma unroll
            for (int i = 0; i < 2; ++i) {
                a0[i] = *(const bf16x8*)(ab + (4 + i) * 1024 + o0);
                a1[i] = *(const bf16x8*)(ab + (4 + i) * 1024 + o1);
            }
            if (pf) { stA(t + 1, ns, 1); stA(t + 1, ns, 3); }
            asm volatile("s_waitcnt lgkmcnt(0)" ::: "memory");
            SB0();
            __builtin_amdgcn_s_setprio(1);
            #pragma unroll
            for (int i = 0; i < 2; ++i)
                #pragma unroll
                for (int j = 0; j < 4; ++j) {
                    acc[4 + i][j] = MFMA_BF16(a0[i], b0[j], acc[4 + i][j]);
                    acc[4 + i][j] = MFMA_BF16(a1[i], b1[j], acc[4 + i][j]);
                }
            __builtin_amdgcn_s_setprio(0);
            SB0();
        }

        // ===== F3: A67; vmcnt(2); BARRIER =====
        {
            bf16x8 a0[2], a1[2];
            #pragma unroll
            for (int i = 0; i < 2; ++i) {
                a0[i] = *(const bf16x8*)(ab + (6 + i) * 1024 + o0);
                a1[i] = *(const bf16x8*)(ab + (6 + i) * 1024 + o1);
            }
            asm volatile("s_waitcnt lgkmcnt(0)" ::: "memory");
            SB0();
            __builtin_amdgcn_s_setprio(1);
            #pragma unroll
            for (int i = 0; i < 2; ++i)
                #pragma unroll
                for (int j = 0; j < 4; ++j) {
                    acc[6 + i][j] = MFMA_BF16(a0[i], b0[j], acc[6 + i][j]);
                    acc[6 + i][j] = MFMA_BF16(a1[i], b1[j], acc[6 + i][j]);
                }
            __builtin_amdgcn_s_setprio(0);
            asm volatile("s_waitcnt vmcnt(2)" ::: "memory");
            SB0();
            __builtin_amdgcn_s_barrier();
            SB0();
        }
    }
}

// Generic GEMM. EPI: 1 = sigmoid->bf16; 2 = resid + acc -> fp32;
//                3 = relu(acc)^2 -> bf16; 4 = outF += bf16(mul)*acc
template<int EPI>
__global__ __launch_bounds__(512, 1) void k_gemm(
    const unsigned short* __restrict__ A, int lda,
    const unsigned short* __restrict__ Bw, int ldb,
    int K, int N,
    float* __restrict__ outF, unsigned short* __restrict__ outH,
    const float* __restrict__ resid, const unsigned short* __restrict__ mul)
{
    __shared__ unsigned short As[2 * 16384];   // 64 KiB
    __shared__ unsigned short Bs[2 * 16384];   // 64 KiB
    f32x4 acc[8][4];
    const f32x4 zero = {0.f, 0.f, 0.f, 0.f};
    #pragma unroll
    for (int i = 0; i < 8; ++i)
        #pragma unroll
        for (int j = 0; j < 4; ++j) acc[i][j] = zero;

    const int m0 = blockIdx.x * 256, n0 = blockIdx.y * 256;
    gemm_core256(A, lda, Bw, ldb, K, m0, n0, As, Bs, acc);

    const int lane = threadIdx.x & 63, wave = threadIdx.x >> 6;
    const int quad = lane >> 4, l16 = lane & 15;
    const int wm = (wave >> 2) * 128, wn = (wave & 3) * 64;
    #pragma unroll
    for (int i = 0; i < 8; ++i) {
        const int rowb = m0 + wm + i * 16 + quad * 4;
        #pragma unroll
        for (int j = 0; j < 4; ++j) {
            const int col = n0 + wn + j * 16 + l16;
            #pragma unroll
            for (int r = 0; r < 4; ++r) {
                const size_t idx = (size_t)(rowb + r) * N + col;
                const float v = acc[i][j][r];
                if (EPI == 1)      outH[idx] = f2bf(1.f / (1.f + __expf(-v)));
                else if (EPI == 2) outF[idx] = resid[idx] + v;
                else if (EPI == 3) { const float z = v > 0.f ? v : 0.f; outH[idx] = f2bf(z * z); }
                else               outF[idx] = outF[idx] + bf2f(mul[idx]) * v;
            }
        }
    }
}

// Fused k/v/r projection: one dispatch vs packed [Wk;Wv;Wr] (N=3072).
// n-segment (n0>>10, uniform per block) selects BOTH the A input (xk/xv/xr)
// and the output (k->ok, v->ov, sigmoid(r)->orr). 256-tiles divide 1024.
__global__ __launch_bounds__(512, 1) void k_gemm_kvr(
    const unsigned short* __restrict__ xk, const unsigned short* __restrict__ xv,
    const unsigned short* __restrict__ xr,
    const unsigned short* __restrict__ W3,
    unsigned short* __restrict__ ok, unsigned short* __restrict__ ov,
    unsigned short* __restrict__ orr)
{
    __shared__ unsigned short As[2 * 16384];
    __shared__ unsigned short Bs[2 * 16384];
    f32x4 acc[8][4];
    const f32x4 zero = {0.f, 0.f, 0.f, 0.f};
    #pragma unroll
    for (int i = 0; i < 8; ++i)
        #pragma unroll
        for (int j = 0; j < 4; ++j) acc[i][j] = zero;

    const int m0 = blockIdx.x * 256, n0 = blockIdx.y * 256;
    const int seg = n0 >> 10;                       // 0=k 1=v 2=r
    const unsigned short* A = (seg == 0) ? xk : (seg == 1) ? xv : xr;
    unsigned short* outH    = (seg == 0) ? ok : (seg == 1) ? ov : orr;

    gemm_core256(A, C_, W3, C_, C_, m0, n0, As, Bs, acc);

    const int nl0 = n0 & (C_ - 1);
    const int lane = threadIdx.x & 63, wave = threadIdx.x >> 6;
    const int quad = lane >> 4, l16 = lane & 15;
    const int wm = (wave >> 2) * 128, wn = (wave & 3) * 64;
    #pragma unroll
    for (int i = 0; i < 8; ++i) {
        const int rowb = m0 + wm + i * 16 + quad * 4;
        #pragma unroll
        for (int j = 0; j < 4; ++j) {
            const int col = nl0 + wn + j * 16 + l16;
            #pragma unroll
            for (int r = 0; r < 4; ++r) {
                const size_t idx = (size_t)(rowb + r) * C_ + col;
                float v = acc[i][j][r];
                if (seg == 2) v = 1.f / (1.f + __expf(-v));
                outH[idx] = f2bf(v);
            }
        }
    }
}

// ---------------------------------------------------------------------------
// Workspace layout (peak 154 MB):
//   [0,32)MB    xk   -> WKV states (2MB) -> xk2
//   [32,64)     xv   -> p (Wo input)     -> s2
//   [64,96)     xr   -> kk[0:32MB)
//   [96,128)    sr   -> xr2              -> kk[32:64MB)
//   [128,154)   bf16 weights ([Wk;Wv;Wr] contiguous for fused GEMM)
// k,v (bf16, 32MB each) live in d_out until step 5 overwrites it.
// FFN runs in 2 chunks of F=2048 through the 64MB kk buffer at [64,128).
// ---------------------------------------------------------------------------
extern "C" void kernel_launch(void* const* d_in, const int* in_sizes, int n_in,
                              void* d_out, int out_size, void* d_ws, size_t ws_size,
                              hipStream_t stream)
{
    const float* x      = (const float*)d_in[0];
    const float* ln1w   = (const float*)d_in[1];
    const float* ln1b   = (const float*)d_in[2];
    const float* ln2w   = (const float*)d_in[3];
    const float* ln2b   = (const float*)d_in[4];
    const float* atk    = (const float*)d_in[5];
    const float* atv    = (const float*)d_in[6];
    const float* atr    = (const float*)d_in[7];
    const float* tdec   = (const float*)d_in[8];
    const float* tfirst = (const float*)d_in[9];
    const float* Wk     = (const float*)d_in[10];
    const float* Wv     = (const float*)d_in[11];
    const float* Wr     = (const float*)d_in[12];
    const float* Wo     = (const float*)d_in[13];
    const float* ftk    = (const float*)d_in[14];
    const float* ftr    = (const float*)d_in[15];
    const float* Wkey   = (const float*)d_in[16];
    const float* Wrec   = (const float*)d_in[17];
    const float* Wval   = (const float*)d_in[18];
    float* out = (float*)d_out;

    char* ws = (char*)d_ws;
    const size_t MB = 1ull << 20;
    unsigned short* xk  = (unsigned short*)(ws + 0 * MB);
    unsigned short* xv  = (unsigned short*)(ws + 32 * MB);
    unsigned short* xr  = (unsigned short*)(ws + 64 * MB);
    unsigned short* sr  = (unsigned short*)(ws + 96 * MB);
    unsigned short* wb  = (unsigned short*)(ws + 128 * MB);
    float4* states      = (float4*)(ws + 0 * MB);   // 2MB, xk dead after kvr GEMM
    unsigned short* p   = xv;   // p overwrites xv (dead after kvr GEMM)
    unsigned short* xk2 = xk;                             // [0,32)
    unsigned short* xr2 = (unsigned short*)(ws + 96 * MB); // [96,128), sr dead after wkv_scan
    unsigned short* s2  = (unsigned short*)(ws + 32 * MB); // [32,64), p dead after Wo GEMM
    unsigned short* kk  = (unsigned short*)(ws + 64 * MB); // [64,128), 64MB: 16384 x 2048 bf16
    unsigned short* kb  = (unsigned short*)d_out;             // 32MB
    unsigned short* vb  = (unsigned short*)d_out + (32*MB/2); // 32MB

    unsigned short* W3_b   = wb;                   // [Wk;Wv;Wr] 3072x1024
    unsigned short* Wo_b   = wb + 3 * (1u << 20);
    unsigned short* Wrec_b = wb + 4 * (1u << 20);
    unsigned short* Wkey_b = wb + 5 * (1u << 20);
    unsigned short* Wval_b = wb + 9 * (1u << 20);

    // 1) weights -> bf16
    WSrc wsrc; wsrc.p[0]=Wk; wsrc.p[1]=Wv; wsrc.p[2]=Wr; wsrc.p[3]=Wo;
    wsrc.p[4]=Wrec; wsrc.p[5]=Wkey; wsrc.p[6]=Wval;
    k_convert<<<dim3(13312), dim3(256), 0, stream>>>(wsrc, wb);

    // 2) LN1 + time-shift mix -> xk, xv, xr (bf16), 8 rows per block
    k_ln_mix<1><<<dim3(M_/8), dim3(256), 0, stream>>>(x, ln1w, ln1b, atk, atv, atr, xk, xv, xr);

    // 3) fused k/v/r projections (N=3072): k->kb, v->vb, sigmoid(r)->sr
    k_gemm_kvr<<<dim3(64, 12), dim3(512), 0, stream>>>(xk, xv, xr, W3_b, kb, vb, sr);

    // 4) WKV: chunk-parallel scan
    k_wkv_local<<<dim3(512), dim3(256), 0, stream>>>(kb, vb, tdec, states);
    k_wkv_scan<<<dim3(512), dim3(256), 0, stream>>>(kb, vb, sr, tdec, tfirst, states, p);

    // 5) x1 = x + p @ Wo^T -> d_out (fp32)
    k_gemm<2><<<dim3(64, 4), dim3(512), 0, stream>>>(p, 1024, Wo_b, 1024, 1024, 1024, out, (unsigned short*)nullptr, x, (const unsigned short*)nullptr);

    // 6) LN2 + time-shift mix -> xk2 [0,32), xr2 [96,128) (bf16)
    k_ln_mix<0><<<dim3(M_/8), dim3(256), 0, stream>>>(out, ln2w, ln2b, ftk, (const float*)nullptr, ftr, xk2, (unsigned short*)nullptr, xr2);

    // 7) s2 = sigmoid(xr2 @ Wrec^T) (bf16) -> [32,64); frees xr2 region
    k_gemm<1><<<dim3(64, 4), dim3(512), 0, stream>>>(xr2, 1024, Wrec_b, 1024, 1024, 1024, (float*)nullptr, s2, (const float*)nullptr, (const unsigned short*)nullptr);

    // 8) FFN in 2 chunks of F=2048: kk = relu(xk2@Wkey_c^T)^2 (N=2048),
    //    then out += s2 * (kk @ Wval_c^T) (K=2048)
    for (int c = 0; c < 2; ++c) {
        const unsigned short* WkeyC = Wkey_b + (size_t)c * 2048 * 1024;
        const unsigned short* WvalC = Wval_b + (size_t)c * 2048;
        k_gemm<3><<<dim3(64, 8), dim3(512), 0, stream>>>(xk2, 1024, WkeyC, 1024, 1024, 2048, (float*)nullptr, kk, (const float*)nullptr, (const unsigned short*)nullptr);
        k_gemm<4><<<dim3(64, 4), dim3(512), 0, stream>>>(kk, 2048, WvalC, 4096, 2048, 1024, out, (unsigned short*)nullptr, (const float*)nullptr, s2);
    }
}